// Round 13
// baseline (583.510 us; speedup 1.0000x reference)
//
#include <hip/hip_runtime.h>
#include <math.h>

#define B_ 8
#define N_ 2048
#define D_ 256
#define K_ 8
#define NP_ 1024
#define H_ 128
#define EPS_ 1e-8f
#define NEG_INF_ (-1e30f)

typedef unsigned int uint;
typedef unsigned short ushort;
typedef __attribute__((ext_vector_type(4))) float f32x4;
typedef __attribute__((ext_vector_type(8))) short short8;

__device__ __forceinline__ float gelu_exact(float x) {
    return 0.5f * x * (1.0f + erff(x * 0.70710678118654752440f));
}

__device__ __forceinline__ float dot4(float4 a, float4 b) {
    return a.x * b.x + a.y * b.y + a.z * b.z + a.w * b.w;
}

__device__ __forceinline__ ushort f2bf(float f) {
    uint u = __float_as_uint(f);
    u = (u + 0x7FFFu + ((u >> 16) & 1u)) >> 16;
    return (ushort)u;
}

// async global->LDS, 16B per lane; LDS dest = wave-uniform base + lane*16
__device__ __forceinline__ void gll16(const void* g, void* l) {
    __builtin_amdgcn_global_load_lds(
        (const __attribute__((address_space(1))) unsigned int*)g,
        (__attribute__((address_space(3))) unsigned int*)l, 16, 0, 0);
}

__device__ __forceinline__ float bsum256(float* red, int t, float v) {
    red[t] = v;
    __syncthreads();
#pragma unroll
    for (int s = 128; s > 0; s >>= 1) {
        if (t < s) red[t] += red[t + s];
        __syncthreads();
    }
    float r = red[0];
    __syncthreads();
    return r;
}

__device__ __forceinline__ float bmax256(float* red, int t, float v) {
    red[t] = v;
    __syncthreads();
#pragma unroll
    for (int s = 128; s > 0; s >>= 1) {
        if (t < s) red[t] = fmaxf(red[t], red[t + s]);
        __syncthreads();
    }
    float r = red[0];
    __syncthreads();
    return r;
}

__device__ __forceinline__ uint mono16(uint v) {
    return (v & 0x8000u) ? ((~v) & 0xFFFFu) : (v | 0x8000u);
}

// ---------------- normalize tokens -> tn fp32 + tnbf bf16 ----------------
__global__ __launch_bounds__(256) void k_norm(const float* __restrict__ tokens,
                                              float* __restrict__ tn,
                                              ushort* __restrict__ tnbf) {
    int row = blockIdx.x;
    int t = threadIdx.x;
    __shared__ float red[256];
    float x = tokens[(size_t)row * D_ + t];
    float ss = bsum256(red, t, x * x);
    float nrm = sqrtf(ss) + EPS_;
    float y = x / nrm;
    tn[(size_t)row * D_ + t] = y;
    tnbf[(size_t)row * D_ + t] = f2bf(y);
}

// ================= fused sim-GEMM + exact per-row top-16 =================
#define SCW_ 72
#define INSK_(L) { bool in_ = key > L; uint tm_ = L; L = in_ ? key : L; key = in_ ? tm_ : key; }
#define INS16_ INSK_(l0) INSK_(l1) INSK_(l2) INSK_(l3) INSK_(l4) INSK_(l5) INSK_(l6) INSK_(l7) \
               INSK_(l8) INSK_(l9) INSK_(l10) INSK_(l11) INSK_(l12) INSK_(l13) INSK_(l14) INSK_(l15)
#define INSM_ INSK_(m0) INSK_(m1) INSK_(m2) INSK_(m3) INSK_(m4) INSK_(m5) INSK_(m6) INSK_(m7) \
              INSK_(m8) INSK_(m9) INSK_(m10) INSK_(m11) INSK_(m12) INSK_(m13) INSK_(m14) INSK_(m15)

__global__ __launch_bounds__(256) void k_simtop(const ushort* __restrict__ tnbf,
                                                int* __restrict__ cands) {
    __shared__ __align__(16) char lds[53760];  // As 16K | Bs 32K | sc 32x72 ushort
    char* Bs = lds + 16384;
    ushort* sc = (ushort*)(lds + 49152);
    uint* mg = (uint*)(lds + 16384);  // merge buffer reuses Bs after the loop

    int bid = blockIdx.x;
    int b = bid & 7;          // XCD-pinned batch
    int panel = bid >> 3;     // 0..63
    int i0 = panel * 32;
    int t = threadIdx.x;
    int lane = t & 63;
    int wv = t >> 6;
    int rh = wv & 1, ch = wv >> 1;
    const char* tbb = (const char*)(tnbf + (size_t)b * N_ * D_);

    // stage A panel (32 rows x 512B), pre-swizzled source (slot g holds global g^(row&15))
#pragma unroll
    for (int c = 0; c < 4; ++c) {
        int e = (wv * 4 + c) * 64 + lane;
        int row = e >> 5, g = e & 31;
        gll16(tbb + (size_t)(i0 + row) * 512 + ((g ^ (row & 15)) << 4),
              lds + (wv * 4 + c) * 1024);
    }
    // hoisted per-c source pointers for B staging (advance +32KB per tile)
    const char* gsrc[8];
#pragma unroll
    for (int c = 0; c < 8; ++c) {
        int e = (wv * 8 + c) * 64 + lane;
        int row = e >> 5, g = e & 31;
        gsrc[c] = tbb + (size_t)row * 512 + ((g ^ (row & 15)) << 4);
    }
    // stage B(0) (64 rows x 512B)
#pragma unroll
    for (int c = 0; c < 8; ++c) {
        gll16(gsrc[c], Bs + (wv * 8 + c) * 1024);
        gsrc[c] += 32768;
    }
    asm volatile("s_waitcnt vmcnt(0)" ::: "memory");
    __syncthreads();

    int selrow = t >> 3;  // 0..31
    int selcs = t & 7;
    int gi = i0 + selrow;
    uint l0=0,l1=0,l2=0,l3=0,l4=0,l5=0,l6=0,l7=0,l8=0,l9=0,l10=0,l11=0,l12=0,l13=0,l14=0,l15=0;
    uint rth = 0;  // row threshold (register; refreshed per tile via shfl)

    int arow = rh * 16 + (lane & 15);
    int brow0 = ch * 32 + (lane & 15);
    int brow1 = brow0 + 16;
    int scw = (rh * 16 + (lane >> 4) * 4) * SCW_ + ch * 32 + (lane & 15);

    for (int jt = 0; jt < 32; ++jt) {
        // MFMA: two independent chains (rows rh*16..+15 x cols ch*32..+15 / +16..+31)
        f32x4 acc0 = (f32x4){0.f, 0.f, 0.f, 0.f};
        f32x4 acc1 = (f32x4){0.f, 0.f, 0.f, 0.f};
#pragma unroll
        for (int ks = 0; ks < 8; ++ks) {
            int u = ks * 4 + (lane >> 4);
            short8 af = *(const short8*)(lds + arow * 512 + ((u ^ (arow & 15)) << 4));
            short8 bf0 = *(const short8*)(Bs + brow0 * 512 + ((u ^ (lane & 15)) << 4));
            short8 bf1 = *(const short8*)(Bs + brow1 * 512 + ((u ^ (lane & 15)) << 4));
            acc0 = __builtin_amdgcn_mfma_f32_16x16x32_bf16(af, bf0, acc0, 0, 0, 0);
            acc1 = __builtin_amdgcn_mfma_f32_16x16x32_bf16(af, bf1, acc1, 0, 0, 0);
        }
#pragma unroll
        for (int v = 0; v < 4; ++v) sc[scw + v * SCW_] = f2bf(acc0[v]);
#pragma unroll
        for (int v = 0; v < 4; ++v) sc[scw + v * SCW_ + 16] = f2bf(acc1[v]);
        __syncthreads();  // sc ready; all Bs reads done

        // issue next tile loads: they fly under the selection phase
        if (jt < 31) {
#pragma unroll
            for (int c = 0; c < 8; ++c) {
                gll16(gsrc[c], Bs + (wv * 8 + c) * 1024);
                gsrc[c] += 32768;
            }
        }
        // online selection: 8 threads/row, 8 cols each; gate by max(own l15, row threshold)
        int j0 = jt * 64;
        int sbase = selrow * SCW_;
        uint gate = l15 > rth ? l15 : rth;
#pragma unroll
        for (int jj = 0; jj < 8; ++jj) {
            int col = selcs + jj * 8;
            int j = j0 + col;
            uint sv = sc[sbase + col];
            if (j != gi) {
                uint key = (mono16(sv) << 16) | (65535u - (uint)j);
                if (key > gate) {
                    INS16_
                    gate = l15 > rth ? l15 : rth;
                }
            }
        }
        // refresh row threshold: max of the 8 per-thread l15 (contiguous 8-lane group)
        {
            uint m = l15;
            m = m > (uint)__shfl_xor((int)m, 1) ? m : (uint)__shfl_xor((int)m, 1);
            m = m > (uint)__shfl_xor((int)m, 2) ? m : (uint)__shfl_xor((int)m, 2);
            m = m > (uint)__shfl_xor((int)m, 4) ? m : (uint)__shfl_xor((int)m, 4);
            rth = m;
        }
        asm volatile("s_waitcnt vmcnt(0)" ::: "memory");
        __syncthreads();  // Bs(jt+1) ready, sc consumed
    }

    // merge: 8 sorted lists/row -> exact top-16 (stride-17 kills bank conflict)
    uint* ml = mg + (size_t)t * 17;
    ml[0]=l0; ml[1]=l1; ml[2]=l2; ml[3]=l3; ml[4]=l4; ml[5]=l5; ml[6]=l6; ml[7]=l7;
    ml[8]=l8; ml[9]=l9; ml[10]=l10; ml[11]=l11; ml[12]=l12; ml[13]=l13; ml[14]=l14; ml[15]=l15;
    __syncthreads();
    if (selcs == 0) {
        uint m0=0,m1=0,m2=0,m3=0,m4=0,m5=0,m6=0,m7=0,m8=0,m9=0,m10=0,m11=0,m12=0,m13=0,m14=0,m15=0;
        const uint* base = mg + (size_t)(selrow * 8) * 17;
#pragma unroll
        for (int s2 = 0; s2 < 8; ++s2) {
            const uint* lp = base + s2 * 17;
            for (int q = 0; q < 16; ++q) {
                uint key = lp[q];
                if (key <= m15) break;  // lists sorted descending
                INSM_
            }
        }
        int* crow = cands + ((size_t)b * N_ + gi) * 16;
        crow[0]=(int)(65535u-(m0&0xFFFFu));   crow[1]=(int)(65535u-(m1&0xFFFFu));
        crow[2]=(int)(65535u-(m2&0xFFFFu));   crow[3]=(int)(65535u-(m3&0xFFFFu));
        crow[4]=(int)(65535u-(m4&0xFFFFu));   crow[5]=(int)(65535u-(m5&0xFFFFu));
        crow[6]=(int)(65535u-(m6&0xFFFFu));   crow[7]=(int)(65535u-(m7&0xFFFFu));
        crow[8]=(int)(65535u-(m8&0xFFFFu));   crow[9]=(int)(65535u-(m9&0xFFFFu));
        crow[10]=(int)(65535u-(m10&0xFFFFu)); crow[11]=(int)(65535u-(m11&0xFFFFu));
        crow[12]=(int)(65535u-(m12&0xFFFFu)); crow[13]=(int)(65535u-(m13&0xFFFFu));
        crow[14]=(int)(65535u-(m14&0xFFFFu)); crow[15]=(int)(65535u-(m15&0xFFFFu));
    }
}

// ---------------- exact fp32 rescore of 16 candidates -> top-8 ----------------
__global__ __launch_bounds__(64) void k_rescore(const float* __restrict__ tn,
                                                const int* __restrict__ cands,
                                                int* __restrict__ topk) {
    int row = blockIdx.x;
    int b = row >> 11;
    int lane = threadIdx.x;
    int j = cands[(size_t)row * 16 + (lane & 15)];
    float s = 0.f;
    if (lane < 16) {
        const float* ti = tn + (size_t)row * D_;
        const float* tj = tn + ((size_t)(b << 11) + j) * D_;
        for (int d = 0; d < D_; d += 4) {
            float4 u = *(const float4*)(tj + d);
            float4 w = *(const float4*)(ti + d);
            s += dot4(u, w);
        }
    }
    float dv[16];
    int jv[16];
#pragma unroll
    for (int c = 0; c < 16; ++c) {
        dv[c] = __shfl(s, c);
        jv[c] = __shfl(j, c);
    }
    uint used = 0;
    for (int r = 0; r < 8; ++r) {
        float bv = -1e38f;
        int bj = 1 << 30, bc = -1;
#pragma unroll
        for (int c = 0; c < 16; ++c) {
            bool av = !(used & (1u << c));
            bool better = av && (dv[c] > bv || (dv[c] == bv && jv[c] < bj));
            bv = better ? dv[c] : bv;
            bj = better ? jv[c] : bj;
            bc = better ? c : bc;
        }
        used |= 1u << bc;
        if (lane == 0) topk[(size_t)row * K_ + r] = bj;
    }
}

// ---------------- mutual adjacency + degree-normalized aggregation ----------------
__global__ __launch_bounds__(64) void k_adj_agg(const float* __restrict__ tokens,
                                                const int* __restrict__ topk,
                                                int* __restrict__ nbr,
                                                int* __restrict__ deg,
                                                float* __restrict__ agg) {
    int row = blockIdx.x;
    int b = row >> 11;
    int i = row & (N_ - 1);
    int t = threadIdx.x;
    __shared__ int s_cand[K_];
    __shared__ int s_nbr[K_];
    __shared__ int s_deg;
    if (t < K_) {
        int j = topk[(size_t)row * K_ + t];
        const int* tj = topk + ((size_t)(b * N_ + j)) * K_;
        bool mut = false;
#pragma unroll
        for (int k = 0; k < K_; ++k) mut = mut || (tj[k] == i);
        s_cand[t] = mut ? j : -1;
    }
    __syncthreads();
    if (t == 0) {
        int d = 0;
#pragma unroll
        for (int k = 0; k < K_; ++k)
            if (s_cand[k] >= 0) s_nbr[d++] = s_cand[k];
        s_deg = d;
    }
    __syncthreads();
    int dgi = s_deg;
    const float* tb = tokens + (size_t)b * N_ * D_;
    float a0 = 0, a1 = 0, a2 = 0, a3 = 0;
    for (int k = 0; k < dgi; ++k) {
        float4 v = *(const float4*)(tb + (size_t)s_nbr[k] * D_ + t * 4);
        a0 += v.x; a1 += v.y; a2 += v.z; a3 += v.w;
    }
    float inv = 1.0f / (float)(dgi > 0 ? dgi : 1);
    *(float4*)(agg + (size_t)row * D_ + t * 4) = make_float4(a0 * inv, a1 * inv, a2 * inv, a3 * inv);
    if (t < K_) nbr[(size_t)row * K_ + t] = (t < dgi) ? s_nbr[t] : -1;
    if (t == 0) deg[row] = dgi;
}

// ---------------- transpose-cast: tokens [N][D] f32 -> tokT [D][N] bf16 ----------------
__global__ __launch_bounds__(256) void k_tokT(const float* __restrict__ tokens,
                                              ushort* __restrict__ tokT) {
    int b = blockIdx.z;
    int n0 = blockIdx.x * 32, d0 = blockIdx.y * 32;
    __shared__ float tile[32][33];
    int t = threadIdx.x;
#pragma unroll
    for (int q = 0; q < 4; ++q) {
        int e = q * 256 + t;
        int r = e >> 5, c = e & 31;
        tile[r][c] = tokens[((size_t)b * N_ + n0 + r) * D_ + d0 + c];
    }
    __syncthreads();
#pragma unroll
    for (int q = 0; q < 4; ++q) {
        int e = q * 256 + t;
        int r = e >> 5, c = e & 31;
        tokT[((size_t)b * D_ + d0 + r) * N_ + n0 + c] = f2bf(tile[c][r]);
    }
}

// ---------------- transpose-cast: assign [N][NP] f32 -> assignT [NP][N] bf16 ----------------
__global__ __launch_bounds__(256) void k_asT(const float* __restrict__ assign,
                                             ushort* __restrict__ assignT) {
    int b = blockIdx.z;
    int n0 = blockIdx.x * 32, p0 = blockIdx.y * 32;
    __shared__ float tile[32][33];
    int t = threadIdx.x;
#pragma unroll
    for (int q = 0; q < 4; ++q) {
        int e = q * 256 + t;
        int r = e >> 5, c = e & 31;
        tile[r][c] = assign[((size_t)b * N_ + n0 + r) * NP_ + p0 + c];
    }
    __syncthreads();
#pragma unroll
    for (int q = 0; q < 4; ++q) {
        int e = q * 256 + t;
        int r = e >> 5, c = e & 31;
        assignT[((size_t)b * NP_ + p0 + r) * N_ + n0 + c] = f2bf(tile[c][r]);
    }
}

// ======= FUSED MLP1(+GELU) -> MLP2 + softmax + entropy (8 rows/block, 2048 blocks) =======
// Per-row chains bitwise-identical to R12's 16-row version; only row->block grouping differs.
__global__ __launch_bounds__(256) void k_mlp12(const float* __restrict__ tokens,
                                               const float* __restrict__ agg,
                                               const float* __restrict__ W1,
                                               const float* __restrict__ b1,
                                               const float* __restrict__ W2,
                                               const float* __restrict__ b2,
                                               float* __restrict__ assign,
                                               float* __restrict__ ent_partial) {
    int row0 = blockIdx.x * 8;
    int t = threadIdx.x;
    int col = t & 127;
    int half = t >> 7;
    __shared__ __align__(16) char smem[16384];  // feat[8][512] overlaid with hsT[128*20]
    __shared__ float red2[8][256];
    __shared__ float red[256];
    float* feat = (float*)smem;
    float* hsT = (float*)smem;

    // ---- phase 1: mlp1 (identical per-row chain) ----
    for (int e = t; e < 8 * 2 * D_; e += 256) {
        int r = e >> 9, c = e & 511;
        feat[r * 512 + c] = (c < D_) ? tokens[(size_t)(row0 + r) * D_ + c]
                                     : agg[(size_t)(row0 + r) * D_ + (c - D_)];
    }
    __syncthreads();
    const float* fr = feat + (half * 4) * 512;
    float bias = b1[col];
    float a0 = bias, a1 = bias, a2 = bias, a3 = bias;
    for (int i = 0; i < 2 * D_; i += 4) {
        float w0 = W1[(size_t)(i + 0) * H_ + col];
        float w1 = W1[(size_t)(i + 1) * H_ + col];
        float w2 = W1[(size_t)(i + 2) * H_ + col];
        float w3 = W1[(size_t)(i + 3) * H_ + col];
        float4 f0 = *(const float4*)(fr + 0 * 512 + i);
        float4 f1 = *(const float4*)(fr + 1 * 512 + i);
        float4 f2 = *(const float4*)(fr + 2 * 512 + i);
        float4 f3 = *(const float4*)(fr + 3 * 512 + i);
        a0 += f0.x * w0; a0 += f0.y * w1; a0 += f0.z * w2; a0 += f0.w * w3;
        a1 += f1.x * w0; a1 += f1.y * w1; a1 += f1.z * w2; a1 += f1.w * w3;
        a2 += f2.x * w0; a2 += f2.y * w1; a2 += f2.z * w2; a2 += f2.w * w3;
        a3 += f3.x * w0; a3 += f3.y * w1; a3 += f3.z * w2; a3 += f3.w * w3;
    }
    float g0 = gelu_exact(a0), g1 = gelu_exact(a1), g2 = gelu_exact(a2), g3 = gelu_exact(a3);
    __syncthreads();  // all feat reads done; safe to overlay hsT
    {
        int rb = half * 4;
        float* hp = hsT + col * 20 + rb;
        hp[0] = g0; hp[1] = g1; hp[2] = g2; hp[3] = g3;
    }
    __syncthreads();

    // ---- phase 2: mlp2 + softmax (identical per-row chains/trees) ----
    float acc[8][4];
#pragma unroll
    for (int s = 0; s < 4; ++s) {
        float bb = b2[s * 256 + t];
#pragma unroll
        for (int r = 0; r < 8; ++r) acc[r][s] = bb;
    }
#pragma unroll 4
    for (int i = 0; i < H_; ++i) {
        float w0 = W2[(size_t)i * NP_ + t];
        float w1 = W2[(size_t)i * NP_ + 256 + t];
        float w2 = W2[(size_t)i * NP_ + 512 + t];
        float w3 = W2[(size_t)i * NP_ + 768 + t];
        float hv[8];
        *(float4*)&hv[0] = *(const float4*)&hsT[i * 20 + 0];
        *(float4*)&hv[4] = *(const float4*)&hsT[i * 20 + 4];
#pragma unroll
        for (int r = 0; r < 8; ++r) {
            acc[r][0] += hv[r] * w0; acc[r][1] += hv[r] * w1;
            acc[r][2] += hv[r] * w2; acc[r][3] += hv[r] * w3;
        }
    }
    // batched max tree (bitwise == bmax256 per row)
#pragma unroll
    for (int r = 0; r < 8; ++r)
        red2[r][t] = fmaxf(fmaxf(acc[r][0], acc[r][1]), fmaxf(acc[r][2], acc[r][3]));
    __syncthreads();
#pragma unroll
    for (int s = 128; s > 0; s >>= 1) {
        if (t < s) {
#pragma unroll
            for (int r = 0; r < 8; ++r) red2[r][t] = fmaxf(red2[r][t], red2[r][t + s]);
        }
        __syncthreads();
    }
#pragma unroll
    for (int r = 0; r < 8; ++r) {
        float m = red2[r][0];
        acc[r][0] -= m; acc[r][1] -= m; acc[r][2] -= m; acc[r][3] -= m;
    }
    __syncthreads();
    // batched sum tree (bitwise == bsum256 per row)
#pragma unroll
    for (int r = 0; r < 8; ++r)
        red2[r][t] = expf(acc[r][0]) + expf(acc[r][1]) + expf(acc[r][2]) + expf(acc[r][3]);
    __syncthreads();
#pragma unroll
    for (int s = 128; s > 0; s >>= 1) {
        if (t < s) {
#pragma unroll
            for (int r = 0; r < 8; ++r) red2[r][t] += red2[r][t + s];
        }
        __syncthreads();
    }
    float entv = 0.f;
#pragma unroll
    for (int r = 0; r < 8; ++r) {
        float tot = red2[r][0];
        float inv = 1.0f / tot;
        float p0 = expf(acc[r][0]) * inv, p1 = expf(acc[r][1]) * inv;
        float p2 = expf(acc[r][2]) * inv, p3 = expf(acc[r][3]) * inv;
        float* arow = assign + (size_t)(row0 + r) * NP_;
        arow[t] = p0; arow[256 + t] = p1; arow[512 + t] = p2; arow[768 + t] = p3;
        entv -= p0 * logf(p0 + EPS_) + p1 * logf(p1 + EPS_) + p2 * logf(p2 + EPS_) + p3 * logf(p3 + EPS_);
    }
    float bs = bsum256(red, t, entv);
    if (t == 0) ent_partial[blockIdx.x] = bs;
}

// ================= 64x64 MFMA core, double-buffered gload_lds staging =================
__device__ __forceinline__ void stage8k(const ushort* __restrict__ A,
                                        const ushort* __restrict__ B,
                                        int kb, char* lA, char* lB, int wv, int lane) {
#pragma unroll
    for (int c = 0; c < 2; ++c) {
        int e = (wv * 2 + c) * 64 + lane;
        int row = e >> 3, g = e & 7;
        size_t go = (size_t)row * N_ + kb + ((g ^ (row & 7)) << 3);
        gll16(A + go, lA + (wv * 2 + c) * 1024);
        gll16(B + go, lB + (wv * 2 + c) * 1024);
    }
}

__device__ __forceinline__ void gemm64g(const ushort* __restrict__ A,
                                        const ushort* __restrict__ B,
                                        f32x4 acc[2][2], char* lds) {
    int t = threadIdx.x;
    int lane = t & 63;
    int wv = t >> 6;
    int wm = wv >> 1, wn = wv & 1;
    stage8k(A, B, 0, lds, lds + 8192, wv, lane);
    for (int kb = 0; kb < N_; kb += 64) {
        int cur = (kb >> 6) & 1;
        char* lA = lds + cur * 16384;
        char* lB = lA + 8192;
        asm volatile("s_waitcnt vmcnt(0)" ::: "memory");
        __syncthreads();
        if (kb + 64 < N_) {
            char* nA = lds + (cur ^ 1) * 16384;
            stage8k(A, B, kb + 64, nA, nA + 8192, wv, lane);
        }
#pragma unroll
        for (int ks = 0; ks < 2; ++ks) {
            short8 afr[2], bfr[2];
#pragma unroll
            for (int f = 0; f < 2; ++f) {
                int rowA = wm * 32 + f * 16 + (lane & 15);
                int u = ks * 4 + (lane >> 4);
                afr[f] = *(const short8*)(lA + rowA * 128 + ((u ^ (rowA & 7)) << 4));
                int rowB = wn * 32 + f * 16 + (lane & 15);
                bfr[f] = *(const short8*)(lB + rowB * 128 + ((u ^ (rowB & 7)) << 4));
            }
#pragma unroll
            for (int fm = 0; fm < 2; ++fm)
#pragma unroll
                for (int fn = 0; fn < 2; ++fn)
                    acc[fm][fn] = __builtin_amdgcn_mfma_f32_16x16x32_bf16(
                        afr[fm], bfr[fn], acc[fm][fn], 0, 0, 0);
        }
    }
}

// ---------------- pooled = assignT . tokT^T via MFMA 64x64 ----------------
__global__ __launch_bounds__(256) void k_pool64(const ushort* __restrict__ assignT,
                                                const ushort* __restrict__ tokT,
                                                float* __restrict__ pooled) {
    __shared__ __align__(16) char lds[32768];
    int bid = blockIdx.x;
    int b = bid & 7;
    int tile = bid >> 3;
    int p0 = (tile >> 2) * 64, d0 = (tile & 3) * 64;
    const ushort* A = assignT + ((size_t)b * NP_ + p0) * N_;
    const ushort* Bp = tokT + ((size_t)b * D_ + d0) * N_;
    f32x4 acc[2][2];
#pragma unroll
    for (int x = 0; x < 2; ++x)
#pragma unroll
        for (int y = 0; y < 2; ++y) acc[x][y] = (f32x4){0.f, 0.f, 0.f, 0.f};
    gemm64g(A, Bp, acc, lds);
    int lane = threadIdx.x & 63;
    int wid = threadIdx.x >> 6;
    int wm = wid >> 1, wn = wid & 1;
#pragma unroll
    for (int fm = 0; fm < 2; ++fm)
#pragma unroll
        for (int fn = 0; fn < 2; ++fn) {
            int p = p0 + wm * 32 + fm * 16 + (lane >> 4) * 4;
            int d = d0 + wn * 32 + fn * 16 + (lane & 15);
#pragma unroll
            for (int v = 0; v < 4; ++v)
                pooled[((size_t)b * NP_ + p + v) * D_ + d] = acc[fm][fn][v];
        }
}

// ---------------- gram: sum of (A^T A)^2 via MFMA 64x64 triangular tiles ----------------
__global__ __launch_bounds__(256) void k_gram64(const ushort* __restrict__ assignT,
                                                float* __restrict__ gram_partial) {
    __shared__ __align__(16) char lds[32768];
    __shared__ float red[256];
    int bid = blockIdx.x;
    int b = bid & 7;
    int idx = bid >> 3;
    int ti = 0, rem = idx;
    while (rem >= 16 - ti) { rem -= 16 - ti; ++ti; }
    int tj = ti + rem;
    const ushort* A = assignT + ((size_t)b * NP_ + ti * 64) * N_;
    const ushort* Bp = assignT + ((size_t)b * NP_ + tj * 64) * N_;
    f32x4 acc[2][2];
#pragma unroll
    for (int x = 0; x < 2; ++x)
#pragma unroll
        for (int y = 0; y < 2; ++y) acc[x][y] = (f32x4){0.f, 0.f, 0.f, 0.f};
    gemm64g(A, Bp, acc, lds);
    float lsum = 0.f;
#pragma unroll
    for (int x = 0; x < 2; ++x)
#pragma unroll
        for (int y = 0; y < 2; ++y)
#pragma unroll
            for (int v = 0; v < 4; ++v) lsum += acc[x][y][v] * acc[x][y][v];
    float bs = bsum256(red, threadIdx.x, lsum);
    if (threadIdx.x == 0) gram_partial[(size_t)b * 136 + idx] = (ti == tj ? 1.0f : 2.0f) * bs;
}

// ---------------- pooled timestamps: coalesced chunked partials ----------------
__global__ __launch_bounds__(256) void k_poolt_part(const float* __restrict__ assign,
                                                    const float* __restrict__ ts,
                                                    float* __restrict__ part) {
    int bid = blockIdx.x;
    int b = bid & 7, ck = bid >> 3;
    int t = threadIdx.x;
    const float* A = assign + ((size_t)b * N_ + (size_t)ck * 64) * NP_;
    const float* T = ts + (size_t)b * N_ + (size_t)ck * 64;
    float4 acc = make_float4(0.f, 0.f, 0.f, 0.f);
    for (int n = 0; n < 64; ++n) {
        float4 v = *(const float4*)(A + (size_t)n * NP_ + t * 4);
        float tv = T[n];
        acc.x += v.x * tv; acc.y += v.y * tv; acc.z += v.z * tv; acc.w += v.w * tv;
    }
    *(float4*)(part + ((size_t)(b * 32 + ck)) * NP_ + t * 4) = acc;
}

// ---------------- sparse edge term ----------------
__global__ __launch_bounds__(64) void k_edge(const float* __restrict__ assign,
                                             const int* __restrict__ nbr,
                                             const int* __restrict__ deg,
                                             float* __restrict__ edge_partial) {
    int row = blockIdx.x;
    int t = threadIdx.x;
    int dgi = deg[row];
    int b = row >> 11;
    float acc = 0.f;
    if (dgi > 0) {
        const float* ai = assign + (size_t)row * NP_;
        float areg[16];
#pragma unroll
        for (int q = 0; q < 16; ++q) areg[q] = ai[q * 64 + t];
        for (int k = 0; k < dgi; ++k) {
            int j = nbr[(size_t)row * K_ + k];
            const float* aj = assign + ((size_t)(b * N_ + j)) * NP_;
#pragma unroll
            for (int q = 0; q < 16; ++q) acc += areg[q] * aj[q * 64 + t];
        }
    }
#pragma unroll
    for (int s = 32; s > 0; s >>= 1) acc += __shfl_down(acc, s);
    if (t == 0) edge_partial[row] = acc;
}

// ------- per-batch: reduce poolt partials (bitwise == old k_poolt_red) + bitonic sort -------
__global__ __launch_bounds__(256) void k_sort(const float* __restrict__ part,
                                              float* __restrict__ out_pt,
                                              int* __restrict__ sortidx) {
    int b = blockIdx.x;
    int t = threadIdx.x;
    __shared__ float val[NP_];
    __shared__ int sidx[NP_];
    {
        float4 acc = make_float4(0.f, 0.f, 0.f, 0.f);
        for (int ck = 0; ck < 32; ++ck) {
            float4 v = *(const float4*)(part + ((size_t)(b * 32 + ck)) * NP_ + t * 4);
            acc.x += v.x; acc.y += v.y; acc.z += v.z; acc.w += v.w;
        }
        val[t * 4 + 0] = acc.x; val[t * 4 + 1] = acc.y;
        val[t * 4 + 2] = acc.z; val[t * 4 + 3] = acc.w;
        sidx[t * 4 + 0] = t * 4 + 0; sidx[t * 4 + 1] = t * 4 + 1;
        sidx[t * 4 + 2] = t * 4 + 2; sidx[t * 4 + 3] = t * 4 + 3;
    }
    __syncthreads();
    for (int k = 2; k <= NP_; k <<= 1) {
        for (int j = k >> 1; j > 0; j >>= 1) {
            for (int e = t; e < NP_; e += 256) {
                int l = e ^ j;
                if (l > e) {
                    bool up = ((e & k) == 0);
                    float v1 = val[e], v2 = val[l];
                    int i1 = sidx[e], i2 = sidx[l];
                    bool sw = up ? ((v1 > v2) || (v1 == v2 && i1 > i2))
                                 : ((v1 < v2) || (v1 == v2 && i1 < i2));
                    if (sw) { val[e] = v2; val[l] = v1; sidx[e] = i2; sidx[l] = i1; }
                }
            }
            __syncthreads();
        }
    }
    for (int e = t; e < NP_; e += 256) {
        out_pt[(size_t)b * NP_ + e] = val[e];
        sortidx[(size_t)b * NP_ + e] = sidx[e];
    }
}

// ---------------- gather pooled rows in sorted order ----------------
__global__ __launch_bounds__(64) void k_gather(const float* __restrict__ pooledU,
                                               const int* __restrict__ sortidx,
                                               float* __restrict__ out) {
    int bp = blockIdx.x;
    int b = bp >> 10;
    int src = sortidx[bp];
    const float4* s = (const float4*)(pooledU + ((size_t)(b << 10) + src) * D_);
    float4* d = (float4*)(out + (size_t)bp * D_);
    d[threadIdx.x] = s[threadIdx.x];
}

// ---------------- deterministic final reduce ----------------
__global__ __launch_bounds__(256) void k_fin(const float* __restrict__ gram_partial,
                                             const float* __restrict__ edge_partial,
                                             const float* __restrict__ ent_partial,
                                             const int* __restrict__ deg,
                                             float* __restrict__ out2) {
    int t = threadIdx.x;
    __shared__ float red[256];
    float t1 = 0.f, t2 = 0.f, t3 = 0.f, ent = 0.f;
    for (int i = t; i < 136 * B_; i += 256) t1 += gram_partial[i];
    for (int i = t; i < B_ * N_; i += 256) t2 += edge_partial[i];
    for (int i = t; i < (B_ * N_) / 8; i += 256) ent += ent_partial[i];
    for (int i = t; i < B_ * N_; i += 256) t3 += (float)deg[i];
    t1 = bsum256(red, t, t1);
    t2 = bsum256(red, t, t2);
    t3 = bsum256(red, t, t3);
    ent = bsum256(red, t, ent);
    if (t == 0) {
        out2[0] = (t1 - 2.f * t2 + t3) / (float)((size_t)B_ * N_ * N_);
        out2[1] = ent / (float)(B_ * N_);
    }
}

extern "C" void kernel_launch(void* const* d_in, const int* in_sizes, int n_in,
                              void* d_out, int out_size, void* d_ws, size_t ws_size,
                              hipStream_t stream) {
    const float* tokens = (const float*)d_in[0];
    const float* tstamp = (const float*)d_in[1];
    const float* W1 = (const float*)d_in[2];
    const float* b1 = (const float*)d_in[3];
    const float* W2 = (const float*)d_in[4];
    const float* b2 = (const float*)d_in[5];
    float* out = (float*)d_out;

    char* wsp = (char*)d_ws;
    size_t off = 0;
    auto alloc = [&](size_t bytes) -> void* {
        void* p = wsp + off;
        off += (bytes + 255) & ~(size_t)255;
        return p;
    };
    float* tn = (float*)alloc(sizeof(float) * (size_t)B_ * N_ * D_);      // 16.8 MB
    float* agg = tn;  // tn dead after k_rescore
    float* assign = (float*)alloc(sizeof(float) * (size_t)B_ * N_ * NP_); // 67.1 MB
    ushort* tnbf = (ushort*)alloc(sizeof(ushort) * (size_t)B_ * N_ * D_); // 8.4 MB
    ushort* tokT = tnbf;  // tnbf dead after k_simtop
    ushort* assignT = (ushort*)alloc(sizeof(ushort) * (size_t)B_ * NP_ * N_);  // 33.6 MB
    float* pooledU = (float*)alloc(sizeof(float) * (size_t)B_ * NP_ * D_);     // 8.4 MB
    float* poolt_part = (float*)alloc(sizeof(float) * (size_t)B_ * 32 * NP_);  // 1 MB
    int* candbuf = (int*)alloc(sizeof(int) * (size_t)B_ * N_ * 16);
    int* topkbuf = (int*)alloc(sizeof(int) * (size_t)B_ * N_ * K_);
    int* nbrbuf = (int*)alloc(sizeof(int) * (size_t)B_ * N_ * K_);
    int* degbuf = (int*)alloc(sizeof(int) * (size_t)B_ * N_);
    int* sortidx = (int*)alloc(sizeof(int) * (size_t)B_ * NP_);
    float* gram_p = (float*)alloc(sizeof(float) * 136 * B_);
    float* edge_p = (float*)alloc(sizeof(float) * (size_t)B_ * N_);
    float* ent_p = (float*)alloc(sizeof(float) * (size_t)(B_ * N_) / 8);

    k_norm<<<B_ * N_, 256, 0, stream>>>(tokens, tn, tnbf);
    k_simtop<<<512, 256, 0, stream>>>(tnbf, candbuf);
    k_rescore<<<B_ * N_, 64, 0, stream>>>(tn, candbuf, topkbuf);
    k_adj_agg<<<B_ * N_, 64, 0, stream>>>(tokens, topkbuf, nbrbuf, degbuf, agg);
    k_tokT<<<dim3(N_ / 32, D_ / 32, B_), 256, 0, stream>>>(tokens, tokT);
    k_mlp12<<<(B_ * N_) / 8, 256, 0, stream>>>(tokens, agg, W1, b1, W2, b2, assign, ent_p);
    k_asT<<<dim3(N_ / 32, NP_ / 32, B_), 256, 0, stream>>>(assign, assignT);
    k_pool64<<<512, 256, 0, stream>>>(assignT, tokT, pooledU);
    k_poolt_part<<<256, 256, 0, stream>>>(assign, tstamp, poolt_part);
    k_gram64<<<1088, 256, 0, stream>>>(assignT, gram_p);
    k_edge<<<B_ * N_, 64, 0, stream>>>(assign, nbrbuf, degbuf, edge_p);
    k_sort<<<B_, 256, 0, stream>>>(poolt_part, out + (size_t)B_ * NP_ * D_, sortidx);
    k_gather<<<B_ * NP_, 64, 0, stream>>>(pooledU, sortidx, out);
    k_fin<<<1, 256, 0, stream>>>(gram_p, edge_p, ent_p, degbuf,
                                 out + (size_t)B_ * NP_ * D_ + (size_t)B_ * NP_);
}

// Round 14
// 582.154 us; speedup vs baseline: 1.0023x; 1.0023x over previous
//
#include <hip/hip_runtime.h>
#include <math.h>

#define B_ 8
#define N_ 2048
#define D_ 256
#define K_ 8
#define NP_ 1024
#define H_ 128
#define EPS_ 1e-8f
#define NEG_INF_ (-1e30f)

typedef unsigned int uint;
typedef unsigned short ushort;
typedef __attribute__((ext_vector_type(4))) float f32x4;
typedef __attribute__((ext_vector_type(8))) short short8;

__device__ __forceinline__ float gelu_exact(float x) {
    return 0.5f * x * (1.0f + erff(x * 0.70710678118654752440f));
}

__device__ __forceinline__ float dot4(float4 a, float4 b) {
    return a.x * b.x + a.y * b.y + a.z * b.z + a.w * b.w;
}

__device__ __forceinline__ ushort f2bf(float f) {
    uint u = __float_as_uint(f);
    u = (u + 0x7FFFu + ((u >> 16) & 1u)) >> 16;
    return (ushort)u;
}

// async global->LDS, 16B per lane; LDS dest = wave-uniform base + lane*16
__device__ __forceinline__ void gll16(const void* g, void* l) {
    __builtin_amdgcn_global_load_lds(
        (const __attribute__((address_space(1))) unsigned int*)g,
        (__attribute__((address_space(3))) unsigned int*)l, 16, 0, 0);
}

__device__ __forceinline__ float bsum256(float* red, int t, float v) {
    red[t] = v;
    __syncthreads();
#pragma unroll
    for (int s = 128; s > 0; s >>= 1) {
        if (t < s) red[t] += red[t + s];
        __syncthreads();
    }
    float r = red[0];
    __syncthreads();
    return r;
}

__device__ __forceinline__ float bmax256(float* red, int t, float v) {
    red[t] = v;
    __syncthreads();
#pragma unroll
    for (int s = 128; s > 0; s >>= 1) {
        if (t < s) red[t] = fmaxf(red[t], red[t + s]);
        __syncthreads();
    }
    float r = red[0];
    __syncthreads();
    return r;
}

__device__ __forceinline__ uint mono16(uint v) {
    return (v & 0x8000u) ? ((~v) & 0xFFFFu) : (v | 0x8000u);
}

// ---------------- normalize tokens -> tn fp32 + tnbf bf16 ----------------
__global__ __launch_bounds__(256) void k_norm(const float* __restrict__ tokens,
                                              float* __restrict__ tn,
                                              ushort* __restrict__ tnbf) {
    int row = blockIdx.x;
    int t = threadIdx.x;
    __shared__ float red[256];
    float x = tokens[(size_t)row * D_ + t];
    float ss = bsum256(red, t, x * x);
    float nrm = sqrtf(ss) + EPS_;
    float y = x / nrm;
    tn[(size_t)row * D_ + t] = y;
    tnbf[(size_t)row * D_ + t] = f2bf(y);
}

// ================= fused sim-GEMM + exact per-row top-16 =================
#define SCW_ 72
#define INSK_(L) { bool in_ = key > L; uint tm_ = L; L = in_ ? key : L; key = in_ ? tm_ : key; }
#define INS16_ INSK_(l0) INSK_(l1) INSK_(l2) INSK_(l3) INSK_(l4) INSK_(l5) INSK_(l6) INSK_(l7) \
               INSK_(l8) INSK_(l9) INSK_(l10) INSK_(l11) INSK_(l12) INSK_(l13) INSK_(l14) INSK_(l15)
#define INSM_ INSK_(m0) INSK_(m1) INSK_(m2) INSK_(m3) INSK_(m4) INSK_(m5) INSK_(m6) INSK_(m7) \
              INSK_(m8) INSK_(m9) INSK_(m10) INSK_(m11) INSK_(m12) INSK_(m13) INSK_(m14) INSK_(m15)

__global__ __launch_bounds__(256) void k_simtop(const ushort* __restrict__ tnbf,
                                                int* __restrict__ cands) {
    __shared__ __align__(16) char lds[53760];  // As 16K | Bs 32K | sc 32x72 ushort
    char* Bs = lds + 16384;
    ushort* sc = (ushort*)(lds + 49152);
    uint* mg = (uint*)(lds + 16384);  // merge buffer reuses Bs after the loop

    int bid = blockIdx.x;
    int b = bid & 7;          // XCD-pinned batch
    int panel = bid >> 3;     // 0..63
    int i0 = panel * 32;
    int t = threadIdx.x;
    int lane = t & 63;
    int wv = t >> 6;
    int rh = wv & 1, ch = wv >> 1;
    const char* tbb = (const char*)(tnbf + (size_t)b * N_ * D_);

    // stage A panel (32 rows x 512B), pre-swizzled source (slot g holds global g^(row&15))
#pragma unroll
    for (int c = 0; c < 4; ++c) {
        int e = (wv * 4 + c) * 64 + lane;
        int row = e >> 5, g = e & 31;
        gll16(tbb + (size_t)(i0 + row) * 512 + ((g ^ (row & 15)) << 4),
              lds + (wv * 4 + c) * 1024);
    }
    // hoisted per-c source pointers for B staging (advance +32KB per tile)
    const char* gsrc[8];
#pragma unroll
    for (int c = 0; c < 8; ++c) {
        int e = (wv * 8 + c) * 64 + lane;
        int row = e >> 5, g = e & 31;
        gsrc[c] = tbb + (size_t)row * 512 + ((g ^ (row & 15)) << 4);
    }
    // stage B(0) (64 rows x 512B)
#pragma unroll
    for (int c = 0; c < 8; ++c) {
        gll16(gsrc[c], Bs + (wv * 8 + c) * 1024);
        gsrc[c] += 32768;
    }
    asm volatile("s_waitcnt vmcnt(0)" ::: "memory");
    __syncthreads();

    int selrow = t >> 3;  // 0..31
    int selcs = t & 7;
    int gi = i0 + selrow;
    uint l0=0,l1=0,l2=0,l3=0,l4=0,l5=0,l6=0,l7=0,l8=0,l9=0,l10=0,l11=0,l12=0,l13=0,l14=0,l15=0;
    uint rth = 0;  // row threshold (register; refreshed per tile via shfl)

    int arow = rh * 16 + (lane & 15);
    int brow0 = ch * 32 + (lane & 15);
    int brow1 = brow0 + 16;
    int scw = (rh * 16 + (lane >> 4) * 4) * SCW_ + ch * 32 + (lane & 15);

    for (int jt = 0; jt < 32; ++jt) {
        // MFMA: two independent chains (rows rh*16..+15 x cols ch*32..+15 / +16..+31)
        f32x4 acc0 = (f32x4){0.f, 0.f, 0.f, 0.f};
        f32x4 acc1 = (f32x4){0.f, 0.f, 0.f, 0.f};
#pragma unroll
        for (int ks = 0; ks < 8; ++ks) {
            int u = ks * 4 + (lane >> 4);
            short8 af = *(const short8*)(lds + arow * 512 + ((u ^ (arow & 15)) << 4));
            short8 bf0 = *(const short8*)(Bs + brow0 * 512 + ((u ^ (lane & 15)) << 4));
            short8 bf1 = *(const short8*)(Bs + brow1 * 512 + ((u ^ (lane & 15)) << 4));
            acc0 = __builtin_amdgcn_mfma_f32_16x16x32_bf16(af, bf0, acc0, 0, 0, 0);
            acc1 = __builtin_amdgcn_mfma_f32_16x16x32_bf16(af, bf1, acc1, 0, 0, 0);
        }
#pragma unroll
        for (int v = 0; v < 4; ++v) sc[scw + v * SCW_] = f2bf(acc0[v]);
#pragma unroll
        for (int v = 0; v < 4; ++v) sc[scw + v * SCW_ + 16] = f2bf(acc1[v]);
        __syncthreads();  // sc ready; all Bs reads done

        // issue next tile loads: they fly under the selection phase
        if (jt < 31) {
#pragma unroll
            for (int c = 0; c < 8; ++c) {
                gll16(gsrc[c], Bs + (wv * 8 + c) * 1024);
                gsrc[c] += 32768;
            }
        }
        // online selection: 8 threads/row, 8 cols each; gate by max(own l15, row threshold)
        int j0 = jt * 64;
        int sbase = selrow * SCW_;
        uint gate = l15 > rth ? l15 : rth;
#pragma unroll
        for (int jj = 0; jj < 8; ++jj) {
            int col = selcs + jj * 8;
            int j = j0 + col;
            uint sv = sc[sbase + col];
            if (j != gi) {
                uint key = (mono16(sv) << 16) | (65535u - (uint)j);
                if (key > gate) {
                    INS16_
                    gate = l15 > rth ? l15 : rth;
                }
            }
        }
        // refresh row threshold: max of the 8 per-thread l15 (contiguous 8-lane group)
        {
            uint m = l15;
            m = m > (uint)__shfl_xor((int)m, 1) ? m : (uint)__shfl_xor((int)m, 1);
            m = m > (uint)__shfl_xor((int)m, 2) ? m : (uint)__shfl_xor((int)m, 2);
            m = m > (uint)__shfl_xor((int)m, 4) ? m : (uint)__shfl_xor((int)m, 4);
            rth = m;
        }
        asm volatile("s_waitcnt vmcnt(0)" ::: "memory");
        __syncthreads();  // Bs(jt+1) ready, sc consumed
    }

    // merge: 8 sorted lists/row -> exact top-16 (stride-17 kills bank conflict)
    uint* ml = mg + (size_t)t * 17;
    ml[0]=l0; ml[1]=l1; ml[2]=l2; ml[3]=l3; ml[4]=l4; ml[5]=l5; ml[6]=l6; ml[7]=l7;
    ml[8]=l8; ml[9]=l9; ml[10]=l10; ml[11]=l11; ml[12]=l12; ml[13]=l13; ml[14]=l14; ml[15]=l15;
    __syncthreads();
    if (selcs == 0) {
        uint m0=0,m1=0,m2=0,m3=0,m4=0,m5=0,m6=0,m7=0,m8=0,m9=0,m10=0,m11=0,m12=0,m13=0,m14=0,m15=0;
        const uint* base = mg + (size_t)(selrow * 8) * 17;
#pragma unroll
        for (int s2 = 0; s2 < 8; ++s2) {
            const uint* lp = base + s2 * 17;
            for (int q = 0; q < 16; ++q) {
                uint key = lp[q];
                if (key <= m15) break;  // lists sorted descending
                INSM_
            }
        }
        int* crow = cands + ((size_t)b * N_ + gi) * 16;
        crow[0]=(int)(65535u-(m0&0xFFFFu));   crow[1]=(int)(65535u-(m1&0xFFFFu));
        crow[2]=(int)(65535u-(m2&0xFFFFu));   crow[3]=(int)(65535u-(m3&0xFFFFu));
        crow[4]=(int)(65535u-(m4&0xFFFFu));   crow[5]=(int)(65535u-(m5&0xFFFFu));
        crow[6]=(int)(65535u-(m6&0xFFFFu));   crow[7]=(int)(65535u-(m7&0xFFFFu));
        crow[8]=(int)(65535u-(m8&0xFFFFu));   crow[9]=(int)(65535u-(m9&0xFFFFu));
        crow[10]=(int)(65535u-(m10&0xFFFFu)); crow[11]=(int)(65535u-(m11&0xFFFFu));
        crow[12]=(int)(65535u-(m12&0xFFFFu)); crow[13]=(int)(65535u-(m13&0xFFFFu));
        crow[14]=(int)(65535u-(m14&0xFFFFu)); crow[15]=(int)(65535u-(m15&0xFFFFu));
    }
}

// ---------------- exact fp32 rescore of 16 candidates -> top-8 ----------------
__global__ __launch_bounds__(64) void k_rescore(const float* __restrict__ tn,
                                                const int* __restrict__ cands,
                                                int* __restrict__ topk) {
    int row = blockIdx.x;
    int b = row >> 11;
    int lane = threadIdx.x;
    int j = cands[(size_t)row * 16 + (lane & 15)];
    float s = 0.f;
    if (lane < 16) {
        const float* ti = tn + (size_t)row * D_;
        const float* tj = tn + ((size_t)(b << 11) + j) * D_;
        for (int d = 0; d < D_; d += 4) {
            float4 u = *(const float4*)(tj + d);
            float4 w = *(const float4*)(ti + d);
            s += dot4(u, w);
        }
    }
    float dv[16];
    int jv[16];
#pragma unroll
    for (int c = 0; c < 16; ++c) {
        dv[c] = __shfl(s, c);
        jv[c] = __shfl(j, c);
    }
    uint used = 0;
    for (int r = 0; r < 8; ++r) {
        float bv = -1e38f;
        int bj = 1 << 30, bc = -1;
#pragma unroll
        for (int c = 0; c < 16; ++c) {
            bool av = !(used & (1u << c));
            bool better = av && (dv[c] > bv || (dv[c] == bv && jv[c] < bj));
            bv = better ? dv[c] : bv;
            bj = better ? jv[c] : bj;
            bc = better ? c : bc;
        }
        used |= 1u << bc;
        if (lane == 0) topk[(size_t)row * K_ + r] = bj;
    }
}

// ---------------- mutual adjacency + degree-normalized aggregation ----------------
__global__ __launch_bounds__(64) void k_adj_agg(const float* __restrict__ tokens,
                                                const int* __restrict__ topk,
                                                int* __restrict__ nbr,
                                                int* __restrict__ deg,
                                                float* __restrict__ agg) {
    int row = blockIdx.x;
    int b = row >> 11;
    int i = row & (N_ - 1);
    int t = threadIdx.x;
    __shared__ int s_cand[K_];
    __shared__ int s_nbr[K_];
    __shared__ int s_deg;
    if (t < K_) {
        int j = topk[(size_t)row * K_ + t];
        const int* tj = topk + ((size_t)(b * N_ + j)) * K_;
        bool mut = false;
#pragma unroll
        for (int k = 0; k < K_; ++k) mut = mut || (tj[k] == i);
        s_cand[t] = mut ? j : -1;
    }
    __syncthreads();
    if (t == 0) {
        int d = 0;
#pragma unroll
        for (int k = 0; k < K_; ++k)
            if (s_cand[k] >= 0) s_nbr[d++] = s_cand[k];
        s_deg = d;
    }
    __syncthreads();
    int dgi = s_deg;
    const float* tb = tokens + (size_t)b * N_ * D_;
    float a0 = 0, a1 = 0, a2 = 0, a3 = 0;
    for (int k = 0; k < dgi; ++k) {
        float4 v = *(const float4*)(tb + (size_t)s_nbr[k] * D_ + t * 4);
        a0 += v.x; a1 += v.y; a2 += v.z; a3 += v.w;
    }
    float inv = 1.0f / (float)(dgi > 0 ? dgi : 1);
    *(float4*)(agg + (size_t)row * D_ + t * 4) = make_float4(a0 * inv, a1 * inv, a2 * inv, a3 * inv);
    if (t < K_) nbr[(size_t)row * K_ + t] = (t < dgi) ? s_nbr[t] : -1;
    if (t == 0) deg[row] = dgi;
}

// ---------------- transpose-cast: tokens [N][D] f32 -> tokT [D][N] bf16 ----------------
__global__ __launch_bounds__(256) void k_tokT(const float* __restrict__ tokens,
                                              ushort* __restrict__ tokT) {
    int b = blockIdx.z;
    int n0 = blockIdx.x * 32, d0 = blockIdx.y * 32;
    __shared__ float tile[32][33];
    int t = threadIdx.x;
#pragma unroll
    for (int q = 0; q < 4; ++q) {
        int e = q * 256 + t;
        int r = e >> 5, c = e & 31;
        tile[r][c] = tokens[((size_t)b * N_ + n0 + r) * D_ + d0 + c];
    }
    __syncthreads();
#pragma unroll
    for (int q = 0; q < 4; ++q) {
        int e = q * 256 + t;
        int r = e >> 5, c = e & 31;
        tokT[((size_t)b * D_ + d0 + r) * N_ + n0 + c] = f2bf(tile[c][r]);
    }
}

// ---------------- transpose-cast: assign [N][NP] f32 -> assignT [NP][N] bf16 ----------------
__global__ __launch_bounds__(256) void k_asT(const float* __restrict__ assign,
                                             ushort* __restrict__ assignT) {
    int b = blockIdx.z;
    int n0 = blockIdx.x * 32, p0 = blockIdx.y * 32;
    __shared__ float tile[32][33];
    int t = threadIdx.x;
#pragma unroll
    for (int q = 0; q < 4; ++q) {
        int e = q * 256 + t;
        int r = e >> 5, c = e & 31;
        tile[r][c] = assign[((size_t)b * N_ + n0 + r) * NP_ + p0 + c];
    }
    __syncthreads();
#pragma unroll
    for (int q = 0; q < 4; ++q) {
        int e = q * 256 + t;
        int r = e >> 5, c = e & 31;
        assignT[((size_t)b * NP_ + p0 + r) * N_ + n0 + c] = f2bf(tile[c][r]);
    }
}

// ======= FUSED MLP1(+GELU) -> MLP2 + softmax + entropy (16 rows/block) =======
// Phase 1 = exact k_mlp1 chain (gelu kept in regs, no global h round-trip).
// Phase 2 = exact k_mlp2f batched-tree body (hsT filled from regs, same bits).
__global__ __launch_bounds__(256) void k_mlp12(const float* __restrict__ tokens,
                                               const float* __restrict__ agg,
                                               const float* __restrict__ W1,
                                               const float* __restrict__ b1,
                                               const float* __restrict__ W2,
                                               const float* __restrict__ b2,
                                               float* __restrict__ assign,
                                               float* __restrict__ ent_partial) {
    int row0 = blockIdx.x * 16;
    int t = threadIdx.x;
    int col = t & 127;
    int half = t >> 7;
    __shared__ __align__(16) char smem[32768];
    __shared__ float red[256];
    float* feat = (float*)smem;            // [16][512], phase 1 only
    float* hsT = (float*)smem;             // [128*20], phase 2 (overlays dead feat)
    float* red2 = (float*)(smem + 10240);  // [16][256]

    // ---- phase 1: mlp1 (identical chain to old k_mlp1) ----
    for (int e = t; e < 16 * 2 * D_; e += 256) {
        int r = e >> 9, c = e & 511;
        feat[r * 512 + c] = (c < D_) ? tokens[(size_t)(row0 + r) * D_ + c]
                                     : agg[(size_t)(row0 + r) * D_ + (c - D_)];
    }
    __syncthreads();
    const float* fr = feat + (half * 8) * 512;
    float bias = b1[col];
    float a0 = bias, a1 = bias, a2 = bias, a3 = bias, a4 = bias, a5 = bias, a6 = bias, a7 = bias;
    for (int i = 0; i < 2 * D_; i += 4) {
        float w0 = W1[(size_t)(i + 0) * H_ + col];
        float w1 = W1[(size_t)(i + 1) * H_ + col];
        float w2 = W1[(size_t)(i + 2) * H_ + col];
        float w3 = W1[(size_t)(i + 3) * H_ + col];
        float4 f0 = *(const float4*)(fr + 0 * 512 + i);
        float4 f1 = *(const float4*)(fr + 1 * 512 + i);
        float4 f2 = *(const float4*)(fr + 2 * 512 + i);
        float4 f3 = *(const float4*)(fr + 3 * 512 + i);
        float4 f4 = *(const float4*)(fr + 4 * 512 + i);
        float4 f5 = *(const float4*)(fr + 5 * 512 + i);
        float4 f6 = *(const float4*)(fr + 6 * 512 + i);
        float4 f7 = *(const float4*)(fr + 7 * 512 + i);
        a0 += f0.x * w0; a0 += f0.y * w1; a0 += f0.z * w2; a0 += f0.w * w3;
        a1 += f1.x * w0; a1 += f1.y * w1; a1 += f1.z * w2; a1 += f1.w * w3;
        a2 += f2.x * w0; a2 += f2.y * w1; a2 += f2.z * w2; a2 += f2.w * w3;
        a3 += f3.x * w0; a3 += f3.y * w1; a3 += f3.z * w2; a3 += f3.w * w3;
        a4 += f4.x * w0; a4 += f4.y * w1; a4 += f4.z * w2; a4 += f4.w * w3;
        a5 += f5.x * w0; a5 += f5.y * w1; a5 += f5.z * w2; a5 += f5.w * w3;
        a6 += f6.x * w0; a6 += f6.y * w1; a6 += f6.z * w2; a6 += f6.w * w3;
        a7 += f7.x * w0; a7 += f7.y * w1; a7 += f7.z * w2; a7 += f7.w * w3;
    }
    float g0 = gelu_exact(a0), g1 = gelu_exact(a1), g2 = gelu_exact(a2), g3 = gelu_exact(a3);
    float g4 = gelu_exact(a4), g5 = gelu_exact(a5), g6 = gelu_exact(a6), g7 = gelu_exact(a7);
    __syncthreads();  // all feat reads done; safe to overlay hsT
    {
        int rb = half * 8;
        float* hp = hsT + col * 20 + rb;  // hsT[i=col][r=rb+v], same layout as old mlp2f
        hp[0] = g0; hp[1] = g1; hp[2] = g2; hp[3] = g3;
        hp[4] = g4; hp[5] = g5; hp[6] = g6; hp[7] = g7;
    }
    __syncthreads();

    // ---- phase 2: mlp2f (identical batched-tree body) ----
    float acc[16][4];
#pragma unroll
    for (int s = 0; s < 4; ++s) {
        float bb = b2[s * 256 + t];
#pragma unroll
        for (int r = 0; r < 16; ++r) acc[r][s] = bb;
    }
#pragma unroll 4
    for (int i = 0; i < H_; ++i) {
        float w0 = W2[(size_t)i * NP_ + t];
        float w1 = W2[(size_t)i * NP_ + 256 + t];
        float w2 = W2[(size_t)i * NP_ + 512 + t];
        float w3 = W2[(size_t)i * NP_ + 768 + t];
        float hv[16];
        *(float4*)&hv[0] = *(const float4*)&hsT[i * 20 + 0];
        *(float4*)&hv[4] = *(const float4*)&hsT[i * 20 + 4];
        *(float4*)&hv[8] = *(const float4*)&hsT[i * 20 + 8];
        *(float4*)&hv[12] = *(const float4*)&hsT[i * 20 + 12];
#pragma unroll
        for (int r = 0; r < 16; ++r) {
            acc[r][0] += hv[r] * w0; acc[r][1] += hv[r] * w1;
            acc[r][2] += hv[r] * w2; acc[r][3] += hv[r] * w3;
        }
    }
    // batched max tree (bitwise == bmax256 per row)
#pragma unroll
    for (int r = 0; r < 16; ++r)
        red2[r * 256 + t] = fmaxf(fmaxf(acc[r][0], acc[r][1]), fmaxf(acc[r][2], acc[r][3]));
    __syncthreads();
#pragma unroll
    for (int s = 128; s > 0; s >>= 1) {
        if (t < s) {
#pragma unroll
            for (int r = 0; r < 16; ++r)
                red2[r * 256 + t] = fmaxf(red2[r * 256 + t], red2[r * 256 + t + s]);
        }
        __syncthreads();
    }
#pragma unroll
    for (int r = 0; r < 16; ++r) {
        float m = red2[r * 256];
        acc[r][0] -= m; acc[r][1] -= m; acc[r][2] -= m; acc[r][3] -= m;
    }
    __syncthreads();
    // batched sum tree (bitwise == bsum256 per row)
#pragma unroll
    for (int r = 0; r < 16; ++r)
        red2[r * 256 + t] = expf(acc[r][0]) + expf(acc[r][1]) + expf(acc[r][2]) + expf(acc[r][3]);
    __syncthreads();
#pragma unroll
    for (int s = 128; s > 0; s >>= 1) {
        if (t < s) {
#pragma unroll
            for (int r = 0; r < 16; ++r) red2[r * 256 + t] += red2[r * 256 + t + s];
        }
        __syncthreads();
    }
    float entv = 0.f;
#pragma unroll
    for (int r = 0; r < 16; ++r) {
        float tot = red2[r * 256];
        float inv = 1.0f / tot;
        float p0 = expf(acc[r][0]) * inv, p1 = expf(acc[r][1]) * inv;
        float p2 = expf(acc[r][2]) * inv, p3 = expf(acc[r][3]) * inv;
        float* arow = assign + (size_t)(row0 + r) * NP_;
        arow[t] = p0; arow[256 + t] = p1; arow[512 + t] = p2; arow[768 + t] = p3;
        entv -= p0 * logf(p0 + EPS_) + p1 * logf(p1 + EPS_) + p2 * logf(p2 + EPS_) + p3 * logf(p3 + EPS_);
    }
    float bs = bsum256(red, t, entv);
    if (t == 0) ent_partial[blockIdx.x] = bs;
}

// ================= 64x64 MFMA core, double-buffered gload_lds staging =================
__device__ __forceinline__ void stage8k(const ushort* __restrict__ A,
                                        const ushort* __restrict__ B,
                                        int kb, char* lA, char* lB, int wv, int lane) {
#pragma unroll
    for (int c = 0; c < 2; ++c) {
        int e = (wv * 2 + c) * 64 + lane;
        int row = e >> 3, g = e & 7;
        size_t go = (size_t)row * N_ + kb + ((g ^ (row & 7)) << 3);
        gll16(A + go, lA + (wv * 2 + c) * 1024);
        gll16(B + go, lB + (wv * 2 + c) * 1024);
    }
}

__device__ __forceinline__ void gemm64g(const ushort* __restrict__ A,
                                        const ushort* __restrict__ B,
                                        f32x4 acc[2][2], char* lds) {
    int t = threadIdx.x;
    int lane = t & 63;
    int wv = t >> 6;
    int wm = wv >> 1, wn = wv & 1;
    stage8k(A, B, 0, lds, lds + 8192, wv, lane);
    for (int kb = 0; kb < N_; kb += 64) {
        int cur = (kb >> 6) & 1;
        char* lA = lds + cur * 16384;
        char* lB = lA + 8192;
        asm volatile("s_waitcnt vmcnt(0)" ::: "memory");
        __syncthreads();
        if (kb + 64 < N_) {
            char* nA = lds + (cur ^ 1) * 16384;
            stage8k(A, B, kb + 64, nA, nA + 8192, wv, lane);
        }
#pragma unroll
        for (int ks = 0; ks < 2; ++ks) {
            short8 afr[2], bfr[2];
#pragma unroll
            for (int f = 0; f < 2; ++f) {
                int rowA = wm * 32 + f * 16 + (lane & 15);
                int u = ks * 4 + (lane >> 4);
                afr[f] = *(const short8*)(lA + rowA * 128 + ((u ^ (rowA & 7)) << 4));
                int rowB = wn * 32 + f * 16 + (lane & 15);
                bfr[f] = *(const short8*)(lB + rowB * 128 + ((u ^ (rowB & 7)) << 4));
            }
#pragma unroll
            for (int fm = 0; fm < 2; ++fm)
#pragma unroll
                for (int fn = 0; fn < 2; ++fn)
                    acc[fm][fn] = __builtin_amdgcn_mfma_f32_16x16x32_bf16(
                        afr[fm], bfr[fn], acc[fm][fn], 0, 0, 0);
        }
    }
}

// ---------------- pooled = assignT . tokT^T via MFMA 64x64 ----------------
__global__ __launch_bounds__(256) void k_pool64(const ushort* __restrict__ assignT,
                                                const ushort* __restrict__ tokT,
                                                float* __restrict__ pooled) {
    __shared__ __align__(16) char lds[32768];
    int bid = blockIdx.x;
    int b = bid & 7;
    int tile = bid >> 3;
    int p0 = (tile >> 2) * 64, d0 = (tile & 3) * 64;
    const ushort* A = assignT + ((size_t)b * NP_ + p0) * N_;
    const ushort* Bp = tokT + ((size_t)b * D_ + d0) * N_;
    f32x4 acc[2][2];
#pragma unroll
    for (int x = 0; x < 2; ++x)
#pragma unroll
        for (int y = 0; y < 2; ++y) acc[x][y] = (f32x4){0.f, 0.f, 0.f, 0.f};
    gemm64g(A, Bp, acc, lds);
    int lane = threadIdx.x & 63;
    int wid = threadIdx.x >> 6;
    int wm = wid >> 1, wn = wid & 1;
#pragma unroll
    for (int fm = 0; fm < 2; ++fm)
#pragma unroll
        for (int fn = 0; fn < 2; ++fn) {
            int p = p0 + wm * 32 + fm * 16 + (lane >> 4) * 4;
            int d = d0 + wn * 32 + fn * 16 + (lane & 15);
#pragma unroll
            for (int v = 0; v < 4; ++v)
                pooled[((size_t)b * NP_ + p + v) * D_ + d] = acc[fm][fn][v];
        }
}

// ---------------- gram: sum of (A^T A)^2 via MFMA 64x64 triangular tiles ----------------
__global__ __launch_bounds__(256) void k_gram64(const ushort* __restrict__ assignT,
                                                float* __restrict__ gram_partial) {
    __shared__ __align__(16) char lds[32768];
    __shared__ float red[256];
    int bid = blockIdx.x;
    int b = bid & 7;
    int idx = bid >> 3;
    int ti = 0, rem = idx;
    while (rem >= 16 - ti) { rem -= 16 - ti; ++ti; }
    int tj = ti + rem;
    const ushort* A = assignT + ((size_t)b * NP_ + ti * 64) * N_;
    const ushort* Bp = assignT + ((size_t)b * NP_ + tj * 64) * N_;
    f32x4 acc[2][2];
#pragma unroll
    for (int x = 0; x < 2; ++x)
#pragma unroll
        for (int y = 0; y < 2; ++y) acc[x][y] = (f32x4){0.f, 0.f, 0.f, 0.f};
    gemm64g(A, Bp, acc, lds);
    float lsum = 0.f;
#pragma unroll
    for (int x = 0; x < 2; ++x)
#pragma unroll
        for (int y = 0; y < 2; ++y)
#pragma unroll
            for (int v = 0; v < 4; ++v) lsum += acc[x][y][v] * acc[x][y][v];
    float bs = bsum256(red, threadIdx.x, lsum);
    if (threadIdx.x == 0) gram_partial[(size_t)b * 136 + idx] = (ti == tj ? 1.0f : 2.0f) * bs;
}

// ---------------- pooled timestamps: coalesced chunked partials ----------------
__global__ __launch_bounds__(256) void k_poolt_part(const float* __restrict__ assign,
                                                    const float* __restrict__ ts,
                                                    float* __restrict__ part) {
    int bid = blockIdx.x;
    int b = bid & 7, ck = bid >> 3;
    int t = threadIdx.x;
    const float* A = assign + ((size_t)b * N_ + (size_t)ck * 64) * NP_;
    const float* T = ts + (size_t)b * N_ + (size_t)ck * 64;
    float4 acc = make_float4(0.f, 0.f, 0.f, 0.f);
    for (int n = 0; n < 64; ++n) {
        float4 v = *(const float4*)(A + (size_t)n * NP_ + t * 4);
        float tv = T[n];
        acc.x += v.x * tv; acc.y += v.y * tv; acc.z += v.z * tv; acc.w += v.w * tv;
    }
    *(float4*)(part + ((size_t)(b * 32 + ck)) * NP_ + t * 4) = acc;
}

// ---------------- sparse edge term ----------------
__global__ __launch_bounds__(64) void k_edge(const float* __restrict__ assign,
                                             const int* __restrict__ nbr,
                                             const int* __restrict__ deg,
                                             float* __restrict__ edge_partial) {
    int row = blockIdx.x;
    int t = threadIdx.x;
    int dgi = deg[row];
    int b = row >> 11;
    float acc = 0.f;
    if (dgi > 0) {
        const float* ai = assign + (size_t)row * NP_;
        float areg[16];
#pragma unroll
        for (int q = 0; q < 16; ++q) areg[q] = ai[q * 64 + t];
        for (int k = 0; k < dgi; ++k) {
            int j = nbr[(size_t)row * K_ + k];
            const float* aj = assign + ((size_t)(b * N_ + j)) * NP_;
#pragma unroll
            for (int q = 0; q < 16; ++q) acc += areg[q] * aj[q * 64 + t];
        }
    }
#pragma unroll
    for (int s = 32; s > 0; s >>= 1) acc += __shfl_down(acc, s);
    if (t == 0) edge_partial[row] = acc;
}

// ------- per-batch: reduce poolt partials (bitwise == old k_poolt_red) + bitonic sort -------
__global__ __launch_bounds__(256) void k_sort(const float* __restrict__ part,
                                              float* __restrict__ out_pt,
                                              int* __restrict__ sortidx) {
    int b = blockIdx.x;
    int t = threadIdx.x;
    __shared__ float val[NP_];
    __shared__ int sidx[NP_];
    {
        float4 acc = make_float4(0.f, 0.f, 0.f, 0.f);
        for (int ck = 0; ck < 32; ++ck) {
            float4 v = *(const float4*)(part + ((size_t)(b * 32 + ck)) * NP_ + t * 4);
            acc.x += v.x; acc.y += v.y; acc.z += v.z; acc.w += v.w;
        }
        val[t * 4 + 0] = acc.x; val[t * 4 + 1] = acc.y;
        val[t * 4 + 2] = acc.z; val[t * 4 + 3] = acc.w;
        sidx[t * 4 + 0] = t * 4 + 0; sidx[t * 4 + 1] = t * 4 + 1;
        sidx[t * 4 + 2] = t * 4 + 2; sidx[t * 4 + 3] = t * 4 + 3;
    }
    __syncthreads();
    for (int k = 2; k <= NP_; k <<= 1) {
        for (int j = k >> 1; j > 0; j >>= 1) {
            for (int e = t; e < NP_; e += 256) {
                int l = e ^ j;
                if (l > e) {
                    bool up = ((e & k) == 0);
                    float v1 = val[e], v2 = val[l];
                    int i1 = sidx[e], i2 = sidx[l];
                    bool sw = up ? ((v1 > v2) || (v1 == v2 && i1 > i2))
                                 : ((v1 < v2) || (v1 == v2 && i1 < i2));
                    if (sw) { val[e] = v2; val[l] = v1; sidx[e] = i2; sidx[l] = i1; }
                }
            }
            __syncthreads();
        }
    }
    for (int e = t; e < NP_; e += 256) {
        out_pt[(size_t)b * NP_ + e] = val[e];
        sortidx[(size_t)b * NP_ + e] = sidx[e];
    }
}

// ---------------- gather pooled rows in sorted order ----------------
__global__ __launch_bounds__(64) void k_gather(const float* __restrict__ pooledU,
                                               const int* __restrict__ sortidx,
                                               float* __restrict__ out) {
    int bp = blockIdx.x;
    int b = bp >> 10;
    int src = sortidx[bp];
    const float4* s = (const float4*)(pooledU + ((size_t)(b << 10) + src) * D_);
    float4* d = (float4*)(out + (size_t)bp * D_);
    d[threadIdx.x] = s[threadIdx.x];
}

// ---------------- deterministic final reduce ----------------
__global__ __launch_bounds__(256) void k_fin(const float* __restrict__ gram_partial,
                                             const float* __restrict__ edge_partial,
                                             const float* __restrict__ ent_partial,
                                             const int* __restrict__ deg,
                                             float* __restrict__ out2) {
    int t = threadIdx.x;
    __shared__ float red[256];
    float t1 = 0.f, t2 = 0.f, t3 = 0.f, ent = 0.f;
    for (int i = t; i < 136 * B_; i += 256) t1 += gram_partial[i];
    for (int i = t; i < B_ * N_; i += 256) t2 += edge_partial[i];
    for (int i = t; i < (B_ * N_) / 16; i += 256) ent += ent_partial[i];
    for (int i = t; i < B_ * N_; i += 256) t3 += (float)deg[i];
    t1 = bsum256(red, t, t1);
    t2 = bsum256(red, t, t2);
    t3 = bsum256(red, t, t3);
    ent = bsum256(red, t, ent);
    if (t == 0) {
        out2[0] = (t1 - 2.f * t2 + t3) / (float)((size_t)B_ * N_ * N_);
        out2[1] = ent / (float)(B_ * N_);
    }
}

extern "C" void kernel_launch(void* const* d_in, const int* in_sizes, int n_in,
                              void* d_out, int out_size, void* d_ws, size_t ws_size,
                              hipStream_t stream) {
    const float* tokens = (const float*)d_in[0];
    const float* tstamp = (const float*)d_in[1];
    const float* W1 = (const float*)d_in[2];
    const float* b1 = (const float*)d_in[3];
    const float* W2 = (const float*)d_in[4];
    const float* b2 = (const float*)d_in[5];
    float* out = (float*)d_out;

    char* wsp = (char*)d_ws;
    size_t off = 0;
    auto alloc = [&](size_t bytes) -> void* {
        void* p = wsp + off;
        off += (bytes + 255) & ~(size_t)255;
        return p;
    };
    float* tn = (float*)alloc(sizeof(float) * (size_t)B_ * N_ * D_);      // 16.8 MB
    float* agg = tn;  // tn dead after k_rescore
    float* assign = (float*)alloc(sizeof(float) * (size_t)B_ * N_ * NP_); // 67.1 MB
    ushort* tnbf = (ushort*)alloc(sizeof(ushort) * (size_t)B_ * N_ * D_); // 8.4 MB
    ushort* tokT = tnbf;  // tnbf dead after k_simtop
    ushort* assignT = (ushort*)alloc(sizeof(ushort) * (size_t)B_ * NP_ * N_);  // 33.6 MB
    float* pooledU = (float*)alloc(sizeof(float) * (size_t)B_ * NP_ * D_);     // 8.4 MB
    float* poolt_part = (float*)alloc(sizeof(float) * (size_t)B_ * 32 * NP_);  // 1 MB
    int* candbuf = (int*)alloc(sizeof(int) * (size_t)B_ * N_ * 16);
    int* topkbuf = (int*)alloc(sizeof(int) * (size_t)B_ * N_ * K_);
    int* nbrbuf = (int*)alloc(sizeof(int) * (size_t)B_ * N_ * K_);
    int* degbuf = (int*)alloc(sizeof(int) * (size_t)B_ * N_);
    int* sortidx = (int*)alloc(sizeof(int) * (size_t)B_ * NP_);
    float* gram_p = (float*)alloc(sizeof(float) * 136 * B_);
    float* edge_p = (float*)alloc(sizeof(float) * (size_t)B_ * N_);
    float* ent_p = (float*)alloc(sizeof(float) * (size_t)(B_ * N_) / 16);

    k_norm<<<B_ * N_, 256, 0, stream>>>(tokens, tn, tnbf);
    k_simtop<<<512, 256, 0, stream>>>(tnbf, candbuf);
    k_rescore<<<B_ * N_, 64, 0, stream>>>(tn, candbuf, topkbuf);
    k_adj_agg<<<B_ * N_, 64, 0, stream>>>(tokens, topkbuf, nbrbuf, degbuf, agg);
    k_tokT<<<dim3(N_ / 32, D_ / 32, B_), 256, 0, stream>>>(tokens, tokT);
    k_mlp12<<<(B_ * N_) / 16, 256, 0, stream>>>(tokens, agg, W1, b1, W2, b2, assign, ent_p);
    k_asT<<<dim3(N_ / 32, NP_ / 32, B_), 256, 0, stream>>>(assign, assignT);
    k_pool64<<<512, 256, 0, stream>>>(assignT, tokT, pooledU);
    k_poolt_part<<<256, 256, 0, stream>>>(assign, tstamp, poolt_part);
    k_gram64<<<1088, 256, 0, stream>>>(assignT, gram_p);
    k_edge<<<B_ * N_, 64, 0, stream>>>(assign, nbrbuf, degbuf, edge_p);
    k_sort<<<B_, 256, 0, stream>>>(poolt_part, out + (size_t)B_ * NP_ * D_, sortidx);
    k_gather<<<B_ * NP_, 64, 0, stream>>>(pooledU, sortidx, out);
    k_fin<<<1, 256, 0, stream>>>(gram_p, edge_p, ent_p, degbuf,
                                 out + (size_t)B_ * NP_ * D_ + (size_t)B_ * NP_);
}

// Round 15
// 506.096 us; speedup vs baseline: 1.1530x; 1.1503x over previous
//
#include <hip/hip_runtime.h>
#include <math.h>

#define B_ 8
#define N_ 2048
#define D_ 256
#define K_ 8
#define NP_ 1024
#define H_ 128
#define EPS_ 1e-8f
#define NEG_INF_ (-1e30f)

typedef unsigned int uint;
typedef unsigned short ushort;
typedef __attribute__((ext_vector_type(4))) float f32x4;
typedef __attribute__((ext_vector_type(8))) short short8;

__device__ __forceinline__ float gelu_exact(float x) {
    return 0.5f * x * (1.0f + erff(x * 0.70710678118654752440f));
}

__device__ __forceinline__ float dot4(float4 a, float4 b) {
    return a.x * b.x + a.y * b.y + a.z * b.z + a.w * b.w;
}

__device__ __forceinline__ ushort f2bf(float f) {
    uint u = __float_as_uint(f);
    u = (u + 0x7FFFu + ((u >> 16) & 1u)) >> 16;
    return (ushort)u;
}

// async global->LDS, 16B per lane; LDS dest = wave-uniform base + lane*16
__device__ __forceinline__ void gll16(const void* g, void* l) {
    __builtin_amdgcn_global_load_lds(
        (const __attribute__((address_space(1))) unsigned int*)g,
        (__attribute__((address_space(3))) unsigned int*)l, 16, 0, 0);
}

__device__ __forceinline__ float bsum256(float* red, int t, float v) {
    red[t] = v;
    __syncthreads();
#pragma unroll
    for (int s = 128; s > 0; s >>= 1) {
        if (t < s) red[t] += red[t + s];
        __syncthreads();
    }
    float r = red[0];
    __syncthreads();
    return r;
}

__device__ __forceinline__ uint mono16(uint v) {
    return (v & 0x8000u) ? ((~v) & 0xFFFFu) : (v | 0x8000u);
}

// ---------------- normalize tokens -> tn fp32 + tnbf bf16 ----------------
__global__ __launch_bounds__(256) void k_norm(const float* __restrict__ tokens,
                                              float* __restrict__ tn,
                                              ushort* __restrict__ tnbf) {
    int row = blockIdx.x;
    int t = threadIdx.x;
    __shared__ float red[256];
    float x = tokens[(size_t)row * D_ + t];
    float ss = bsum256(red, t, x * x);
    float nrm = sqrtf(ss) + EPS_;
    float y = x / nrm;
    tn[(size_t)row * D_ + t] = y;
    tnbf[(size_t)row * D_ + t] = f2bf(y);
}

// ================= fused sim-GEMM + exact per-row top-16 =================
#define SCW_ 72
#define INSK_(L) { bool in_ = key > L; uint tm_ = L; L = in_ ? key : L; key = in_ ? tm_ : key; }
#define INS16_ INSK_(l0) INSK_(l1) INSK_(l2) INSK_(l3) INSK_(l4) INSK_(l5) INSK_(l6) INSK_(l7) \
               INSK_(l8) INSK_(l9) INSK_(l10) INSK_(l11) INSK_(l12) INSK_(l13) INSK_(l14) INSK_(l15)
#define INSM_ INSK_(m0) INSK_(m1) INSK_(m2) INSK_(m3) INSK_(m4) INSK_(m5) INSK_(m6) INSK_(m7) \
              INSK_(m8) INSK_(m9) INSK_(m10) INSK_(m11) INSK_(m12) INSK_(m13) INSK_(m14) INSK_(m15)

__global__ __launch_bounds__(256) void k_simtop(const ushort* __restrict__ tnbf,
                                                int* __restrict__ cands) {
    __shared__ __align__(16) char lds[53760];  // As 16K | Bs 32K | sc 32x72 ushort
    char* Bs = lds + 16384;
    ushort* sc = (ushort*)(lds + 49152);
    uint* mg = (uint*)(lds + 16384);  // merge buffer reuses Bs after the loop

    int bid = blockIdx.x;
    int b = bid & 7;          // XCD-pinned batch
    int panel = bid >> 3;     // 0..63
    int i0 = panel * 32;
    int t = threadIdx.x;
    int lane = t & 63;
    int wv = t >> 6;
    int rh = wv & 1, ch = wv >> 1;
    const char* tbb = (const char*)(tnbf + (size_t)b * N_ * D_);

#pragma unroll
    for (int c = 0; c < 4; ++c) {
        int e = (wv * 4 + c) * 64 + lane;
        int row = e >> 5, g = e & 31;
        gll16(tbb + (size_t)(i0 + row) * 512 + ((g ^ (row & 15)) << 4),
              lds + (wv * 4 + c) * 1024);
    }
    const char* gsrc[8];
#pragma unroll
    for (int c = 0; c < 8; ++c) {
        int e = (wv * 8 + c) * 64 + lane;
        int row = e >> 5, g = e & 31;
        gsrc[c] = tbb + (size_t)row * 512 + ((g ^ (row & 15)) << 4);
    }
#pragma unroll
    for (int c = 0; c < 8; ++c) {
        gll16(gsrc[c], Bs + (wv * 8 + c) * 1024);
        gsrc[c] += 32768;
    }
    asm volatile("s_waitcnt vmcnt(0)" ::: "memory");
    __syncthreads();

    int selrow = t >> 3;
    int selcs = t & 7;
    int gi = i0 + selrow;
    uint l0=0,l1=0,l2=0,l3=0,l4=0,l5=0,l6=0,l7=0,l8=0,l9=0,l10=0,l11=0,l12=0,l13=0,l14=0,l15=0;
    uint rth = 0;

    int arow = rh * 16 + (lane & 15);
    int brow0 = ch * 32 + (lane & 15);
    int brow1 = brow0 + 16;
    int scw = (rh * 16 + (lane >> 4) * 4) * SCW_ + ch * 32 + (lane & 15);

    for (int jt = 0; jt < 32; ++jt) {
        f32x4 acc0 = (f32x4){0.f, 0.f, 0.f, 0.f};
        f32x4 acc1 = (f32x4){0.f, 0.f, 0.f, 0.f};
#pragma unroll
        for (int ks = 0; ks < 8; ++ks) {
            int u = ks * 4 + (lane >> 4);
            short8 af = *(const short8*)(lds + arow * 512 + ((u ^ (arow & 15)) << 4));
            short8 bf0 = *(const short8*)(Bs + brow0 * 512 + ((u ^ (lane & 15)) << 4));
            short8 bf1 = *(const short8*)(Bs + brow1 * 512 + ((u ^ (lane & 15)) << 4));
            acc0 = __builtin_amdgcn_mfma_f32_16x16x32_bf16(af, bf0, acc0, 0, 0, 0);
            acc1 = __builtin_amdgcn_mfma_f32_16x16x32_bf16(af, bf1, acc1, 0, 0, 0);
        }
#pragma unroll
        for (int v = 0; v < 4; ++v) sc[scw + v * SCW_] = f2bf(acc0[v]);
#pragma unroll
        for (int v = 0; v < 4; ++v) sc[scw + v * SCW_ + 16] = f2bf(acc1[v]);
        __syncthreads();

        if (jt < 31) {
#pragma unroll
            for (int c = 0; c < 8; ++c) {
                gll16(gsrc[c], Bs + (wv * 8 + c) * 1024);
                gsrc[c] += 32768;
            }
        }
        int j0 = jt * 64;
        int sbase = selrow * SCW_;
        uint gate = l15 > rth ? l15 : rth;
#pragma unroll
        for (int jj = 0; jj < 8; ++jj) {
            int col = selcs + jj * 8;
            int j = j0 + col;
            uint sv = sc[sbase + col];
            if (j != gi) {
                uint key = (mono16(sv) << 16) | (65535u - (uint)j);
                if (key > gate) {
                    INS16_
                    gate = l15 > rth ? l15 : rth;
                }
            }
        }
        {
            uint m = l15;
            m = m > (uint)__shfl_xor((int)m, 1) ? m : (uint)__shfl_xor((int)m, 1);
            m = m > (uint)__shfl_xor((int)m, 2) ? m : (uint)__shfl_xor((int)m, 2);
            m = m > (uint)__shfl_xor((int)m, 4) ? m : (uint)__shfl_xor((int)m, 4);
            rth = m;
        }
        asm volatile("s_waitcnt vmcnt(0)" ::: "memory");
        __syncthreads();
    }

    uint* ml = mg + (size_t)t * 17;
    ml[0]=l0; ml[1]=l1; ml[2]=l2; ml[3]=l3; ml[4]=l4; ml[5]=l5; ml[6]=l6; ml[7]=l7;
    ml[8]=l8; ml[9]=l9; ml[10]=l10; ml[11]=l11; ml[12]=l12; ml[13]=l13; ml[14]=l14; ml[15]=l15;
    __syncthreads();
    if (selcs == 0) {
        uint m0=0,m1=0,m2=0,m3=0,m4=0,m5=0,m6=0,m7=0,m8=0,m9=0,m10=0,m11=0,m12=0,m13=0,m14=0,m15=0;
        const uint* base = mg + (size_t)(selrow * 8) * 17;
#pragma unroll
        for (int s2 = 0; s2 < 8; ++s2) {
            const uint* lp = base + s2 * 17;
            for (int q = 0; q < 16; ++q) {
                uint key = lp[q];
                if (key <= m15) break;
                INSM_
            }
        }
        int* crow = cands + ((size_t)b * N_ + gi) * 16;
        crow[0]=(int)(65535u-(m0&0xFFFFu));   crow[1]=(int)(65535u-(m1&0xFFFFu));
        crow[2]=(int)(65535u-(m2&0xFFFFu));   crow[3]=(int)(65535u-(m3&0xFFFFu));
        crow[4]=(int)(65535u-(m4&0xFFFFu));   crow[5]=(int)(65535u-(m5&0xFFFFu));
        crow[6]=(int)(65535u-(m6&0xFFFFu));   crow[7]=(int)(65535u-(m7&0xFFFFu));
        crow[8]=(int)(65535u-(m8&0xFFFFu));   crow[9]=(int)(65535u-(m9&0xFFFFu));
        crow[10]=(int)(65535u-(m10&0xFFFFu)); crow[11]=(int)(65535u-(m11&0xFFFFu));
        crow[12]=(int)(65535u-(m12&0xFFFFu)); crow[13]=(int)(65535u-(m13&0xFFFFu));
        crow[14]=(int)(65535u-(m14&0xFFFFu)); crow[15]=(int)(65535u-(m15&0xFFFFu));
    }
}

// ---------------- exact fp32 rescore of 16 candidates -> top-8 ----------------
__global__ __launch_bounds__(64) void k_rescore(const float* __restrict__ tn,
                                                const int* __restrict__ cands,
                                                int* __restrict__ topk) {
    int row = blockIdx.x;
    int b = row >> 11;
    int lane = threadIdx.x;
    int j = cands[(size_t)row * 16 + (lane & 15)];
    float s = 0.f;
    if (lane < 16) {
        const float* ti = tn + (size_t)row * D_;
        const float* tj = tn + ((size_t)(b << 11) + j) * D_;
        for (int d = 0; d < D_; d += 4) {
            float4 u = *(const float4*)(tj + d);
            float4 w = *(const float4*)(ti + d);
            s += dot4(u, w);
        }
    }
    float dv[16];
    int jv[16];
#pragma unroll
    for (int c = 0; c < 16; ++c) {
        dv[c] = __shfl(s, c);
        jv[c] = __shfl(j, c);
    }
    uint used = 0;
    for (int r = 0; r < 8; ++r) {
        float bv = -1e38f;
        int bj = 1 << 30, bc = -1;
#pragma unroll
        for (int c = 0; c < 16; ++c) {
            bool av = !(used & (1u << c));
            bool better = av && (dv[c] > bv || (dv[c] == bv && jv[c] < bj));
            bv = better ? dv[c] : bv;
            bj = better ? jv[c] : bj;
            bc = better ? c : bc;
        }
        used |= 1u << bc;
        if (lane == 0) topk[(size_t)row * K_ + r] = bj;
    }
}

// ---------------- mutual adjacency + degree-normalized aggregation ----------------
__global__ __launch_bounds__(64) void k_adj_agg(const float* __restrict__ tokens,
                                                const int* __restrict__ topk,
                                                int* __restrict__ nbr,
                                                int* __restrict__ deg,
                                                float* __restrict__ agg) {
    int row = blockIdx.x;
    int b = row >> 11;
    int i = row & (N_ - 1);
    int t = threadIdx.x;
    __shared__ int s_cand[K_];
    __shared__ int s_nbr[K_];
    __shared__ int s_deg;
    if (t < K_) {
        int j = topk[(size_t)row * K_ + t];
        const int* tj = topk + ((size_t)(b * N_ + j)) * K_;
        bool mut = false;
#pragma unroll
        for (int k = 0; k < K_; ++k) mut = mut || (tj[k] == i);
        s_cand[t] = mut ? j : -1;
    }
    __syncthreads();
    if (t == 0) {
        int d = 0;
#pragma unroll
        for (int k = 0; k < K_; ++k)
            if (s_cand[k] >= 0) s_nbr[d++] = s_cand[k];
        s_deg = d;
    }
    __syncthreads();
    int dgi = s_deg;
    const float* tb = tokens + (size_t)b * N_ * D_;
    float a0 = 0, a1 = 0, a2 = 0, a3 = 0;
    for (int k = 0; k < dgi; ++k) {
        float4 v = *(const float4*)(tb + (size_t)s_nbr[k] * D_ + t * 4);
        a0 += v.x; a1 += v.y; a2 += v.z; a3 += v.w;
    }
    float inv = 1.0f / (float)(dgi > 0 ? dgi : 1);
    *(float4*)(agg + (size_t)row * D_ + t * 4) = make_float4(a0 * inv, a1 * inv, a2 * inv, a3 * inv);
    if (t < K_) nbr[(size_t)row * K_ + t] = (t < dgi) ? s_nbr[t] : -1;
    if (t == 0) deg[row] = dgi;
}

// ---------------- transpose-cast: assign [N][NP] f32 -> assignT [NP][N] bf16 ----------------
__global__ __launch_bounds__(256) void k_asT(const float* __restrict__ assign,
                                             ushort* __restrict__ assignT) {
    int b = blockIdx.z;
    int n0 = blockIdx.x * 32, p0 = blockIdx.y * 32;
    __shared__ float tile[32][33];
    int t = threadIdx.x;
#pragma unroll
    for (int q = 0; q < 4; ++q) {
        int e = q * 256 + t;
        int r = e >> 5, c = e & 31;
        tile[r][c] = assign[((size_t)b * N_ + n0 + r) * NP_ + p0 + c];
    }
    __syncthreads();
#pragma unroll
    for (int q = 0; q < 4; ++q) {
        int e = q * 256 + t;
        int r = e >> 5, c = e & 31;
        assignT[((size_t)b * NP_ + p0 + r) * N_ + n0 + c] = f2bf(tile[c][r]);
    }
}

// ======= FUSED dispatch: MLP12 (blocks 0..1023) | tokT (blocks 1024..5119) =======
__global__ __launch_bounds__(256) void k_m12t(const float* __restrict__ tokens,
                                              const float* __restrict__ agg,
                                              const float* __restrict__ W1,
                                              const float* __restrict__ b1,
                                              const float* __restrict__ W2,
                                              const float* __restrict__ b2,
                                              float* __restrict__ assign,
                                              float* __restrict__ ent_partial,
                                              ushort* __restrict__ tokT) {
    __shared__ __align__(16) char smem[32768];
    __shared__ float red[256];
    int t = threadIdx.x;
    if (blockIdx.x >= 1024) {
        // ---- tokT body (identical to old k_tokT) ----
        int sub = blockIdx.x - 1024;
        int b = sub >> 9;
        int d0 = ((sub >> 6) & 7) * 32;
        int n0 = (sub & 63) * 32;
        float* tile = (float*)smem;  // [32][33]
#pragma unroll
        for (int q = 0; q < 4; ++q) {
            int e = q * 256 + t;
            int r = e >> 5, c = e & 31;
            tile[r * 33 + c] = tokens[((size_t)b * N_ + n0 + r) * D_ + d0 + c];
        }
        __syncthreads();
#pragma unroll
        for (int q = 0; q < 4; ++q) {
            int e = q * 256 + t;
            int r = e >> 5, c = e & 31;
            tokT[((size_t)b * D_ + d0 + r) * N_ + n0 + c] = f2bf(tile[c * 33 + r]);
        }
        return;
    }
    // ---- mlp12 body (identical to R12/R14 k_mlp12) ----
    int row0 = blockIdx.x * 16;
    int col = t & 127;
    int half = t >> 7;
    float* feat = (float*)smem;
    float* hsT = (float*)smem;
    float* red2 = (float*)(smem + 10240);

    for (int e = t; e < 16 * 2 * D_; e += 256) {
        int r = e >> 9, c = e & 511;
        feat[r * 512 + c] = (c < D_) ? tokens[(size_t)(row0 + r) * D_ + c]
                                     : agg[(size_t)(row0 + r) * D_ + (c - D_)];
    }
    __syncthreads();
    const float* fr = feat + (half * 8) * 512;
    float bias = b1[col];
    float a0 = bias, a1 = bias, a2 = bias, a3 = bias, a4 = bias, a5 = bias, a6 = bias, a7 = bias;
    for (int i = 0; i < 2 * D_; i += 4) {
        float w0 = W1[(size_t)(i + 0) * H_ + col];
        float w1 = W1[(size_t)(i + 1) * H_ + col];
        float w2 = W1[(size_t)(i + 2) * H_ + col];
        float w3 = W1[(size_t)(i + 3) * H_ + col];
        float4 f0 = *(const float4*)(fr + 0 * 512 + i);
        float4 f1 = *(const float4*)(fr + 1 * 512 + i);
        float4 f2 = *(const float4*)(fr + 2 * 512 + i);
        float4 f3 = *(const float4*)(fr + 3 * 512 + i);
        float4 f4 = *(const float4*)(fr + 4 * 512 + i);
        float4 f5 = *(const float4*)(fr + 5 * 512 + i);
        float4 f6 = *(const float4*)(fr + 6 * 512 + i);
        float4 f7 = *(const float4*)(fr + 7 * 512 + i);
        a0 += f0.x * w0; a0 += f0.y * w1; a0 += f0.z * w2; a0 += f0.w * w3;
        a1 += f1.x * w0; a1 += f1.y * w1; a1 += f1.z * w2; a1 += f1.w * w3;
        a2 += f2.x * w0; a2 += f2.y * w1; a2 += f2.z * w2; a2 += f2.w * w3;
        a3 += f3.x * w0; a3 += f3.y * w1; a3 += f3.z * w2; a3 += f3.w * w3;
        a4 += f4.x * w0; a4 += f4.y * w1; a4 += f4.z * w2; a4 += f4.w * w3;
        a5 += f5.x * w0; a5 += f5.y * w1; a5 += f5.z * w2; a5 += f5.w * w3;
        a6 += f6.x * w0; a6 += f6.y * w1; a6 += f6.z * w2; a6 += f6.w * w3;
        a7 += f7.x * w0; a7 += f7.y * w1; a7 += f7.z * w2; a7 += f7.w * w3;
    }
    float g0 = gelu_exact(a0), g1 = gelu_exact(a1), g2 = gelu_exact(a2), g3 = gelu_exact(a3);
    float g4 = gelu_exact(a4), g5 = gelu_exact(a5), g6 = gelu_exact(a6), g7 = gelu_exact(a7);
    __syncthreads();
    {
        int rb = half * 8;
        float* hp = hsT + col * 20 + rb;
        hp[0] = g0; hp[1] = g1; hp[2] = g2; hp[3] = g3;
        hp[4] = g4; hp[5] = g5; hp[6] = g6; hp[7] = g7;
    }
    __syncthreads();

    float acc[16][4];
#pragma unroll
    for (int s = 0; s < 4; ++s) {
        float bb = b2[s * 256 + t];
#pragma unroll
        for (int r = 0; r < 16; ++r) acc[r][s] = bb;
    }
#pragma unroll 4
    for (int i = 0; i < H_; ++i) {
        float w0 = W2[(size_t)i * NP_ + t];
        float w1 = W2[(size_t)i * NP_ + 256 + t];
        float w2 = W2[(size_t)i * NP_ + 512 + t];
        float w3 = W2[(size_t)i * NP_ + 768 + t];
        float hv[16];
        *(float4*)&hv[0] = *(const float4*)&hsT[i * 20 + 0];
        *(float4*)&hv[4] = *(const float4*)&hsT[i * 20 + 4];
        *(float4*)&hv[8] = *(const float4*)&hsT[i * 20 + 8];
        *(float4*)&hv[12] = *(const float4*)&hsT[i * 20 + 12];
#pragma unroll
        for (int r = 0; r < 16; ++r) {
            acc[r][0] += hv[r] * w0; acc[r][1] += hv[r] * w1;
            acc[r][2] += hv[r] * w2; acc[r][3] += hv[r] * w3;
        }
    }
#pragma unroll
    for (int r = 0; r < 16; ++r)
        red2[r * 256 + t] = fmaxf(fmaxf(acc[r][0], acc[r][1]), fmaxf(acc[r][2], acc[r][3]));
    __syncthreads();
#pragma unroll
    for (int s = 128; s > 0; s >>= 1) {
        if (t < s) {
#pragma unroll
            for (int r = 0; r < 16; ++r)
                red2[r * 256 + t] = fmaxf(red2[r * 256 + t], red2[r * 256 + t + s]);
        }
        __syncthreads();
    }
#pragma unroll
    for (int r = 0; r < 16; ++r) {
        float m = red2[r * 256];
        acc[r][0] -= m; acc[r][1] -= m; acc[r][2] -= m; acc[r][3] -= m;
    }
    __syncthreads();
#pragma unroll
    for (int r = 0; r < 16; ++r)
        red2[r * 256 + t] = expf(acc[r][0]) + expf(acc[r][1]) + expf(acc[r][2]) + expf(acc[r][3]);
    __syncthreads();
#pragma unroll
    for (int s = 128; s > 0; s >>= 1) {
        if (t < s) {
#pragma unroll
            for (int r = 0; r < 16; ++r) red2[r * 256 + t] += red2[r * 256 + t + s];
        }
        __syncthreads();
    }
    float entv = 0.f;
#pragma unroll
    for (int r = 0; r < 16; ++r) {
        float tot = red2[r * 256];
        float inv = 1.0f / tot;
        float p0 = expf(acc[r][0]) * inv, p1 = expf(acc[r][1]) * inv;
        float p2 = expf(acc[r][2]) * inv, p3 = expf(acc[r][3]) * inv;
        float* arow = assign + (size_t)(row0 + r) * NP_;
        arow[t] = p0; arow[256 + t] = p1; arow[512 + t] = p2; arow[768 + t] = p3;
        entv -= p0 * logf(p0 + EPS_) + p1 * logf(p1 + EPS_) + p2 * logf(p2 + EPS_) + p3 * logf(p3 + EPS_);
    }
    float bs = bsum256(red, t, entv);
    if (t == 0) ent_partial[blockIdx.x] = bs;
}

// ================= 64x64 MFMA core, double-buffered gload_lds staging =================
__device__ __forceinline__ void stage8k(const ushort* __restrict__ A,
                                        const ushort* __restrict__ B,
                                        int kb, char* lA, char* lB, int wv, int lane) {
#pragma unroll
    for (int c = 0; c < 2; ++c) {
        int e = (wv * 2 + c) * 64 + lane;
        int row = e >> 3, g = e & 7;
        size_t go = (size_t)row * N_ + kb + ((g ^ (row & 7)) << 3);
        gll16(A + go, lA + (wv * 2 + c) * 1024);
        gll16(B + go, lB + (wv * 2 + c) * 1024);
    }
}

__device__ __forceinline__ void gemm64g(const ushort* __restrict__ A,
                                        const ushort* __restrict__ B,
                                        f32x4 acc[2][2], char* lds) {
    int t = threadIdx.x;
    int lane = t & 63;
    int wv = t >> 6;
    int wm = wv >> 1, wn = wv & 1;
    stage8k(A, B, 0, lds, lds + 8192, wv, lane);
    for (int kb = 0; kb < N_; kb += 64) {
        int cur = (kb >> 6) & 1;
        char* lA = lds + cur * 16384;
        char* lB = lA + 8192;
        asm volatile("s_waitcnt vmcnt(0)" ::: "memory");
        __syncthreads();
        if (kb + 64 < N_) {
            char* nA = lds + (cur ^ 1) * 16384;
            stage8k(A, B, kb + 64, nA, nA + 8192, wv, lane);
        }
#pragma unroll
        for (int ks = 0; ks < 2; ++ks) {
            short8 afr[2], bfr[2];
#pragma unroll
            for (int f = 0; f < 2; ++f) {
                int rowA = wm * 32 + f * 16 + (lane & 15);
                int u = ks * 4 + (lane >> 4);
                afr[f] = *(const short8*)(lA + rowA * 128 + ((u ^ (rowA & 7)) << 4));
                int rowB = wn * 32 + f * 16 + (lane & 15);
                bfr[f] = *(const short8*)(lB + rowB * 128 + ((u ^ (rowB & 7)) << 4));
            }
#pragma unroll
            for (int fm = 0; fm < 2; ++fm)
#pragma unroll
                for (int fn = 0; fn < 2; ++fn)
                    acc[fm][fn] = __builtin_amdgcn_mfma_f32_16x16x32_bf16(
                        afr[fm], bfr[fn], acc[fm][fn], 0, 0, 0);
        }
    }
}

// === FUSED dispatch: gram64 (0..1087) | pool64 (1088..1599) | poolt (1600..1855) | edge (1856..5951) ===
__global__ __launch_bounds__(256) void k_fuse4(const ushort* __restrict__ assignT,
                                               const ushort* __restrict__ tokT,
                                               const float* __restrict__ assign,
                                               const float* __restrict__ tstamp,
                                               const int* __restrict__ nbr,
                                               const int* __restrict__ deg,
                                               float* __restrict__ pooled,
                                               float* __restrict__ part,
                                               float* __restrict__ gram_partial,
                                               float* __restrict__ edge_partial) {
    __shared__ __align__(16) char lds[32768];
    __shared__ float red[256];
    int bid = blockIdx.x;
    int t = threadIdx.x;
    if (bid < 1088) {
        // ---- gram64 body (identical) ----
        int b = bid & 7;
        int idx = bid >> 3;
        int ti = 0, rem = idx;
        while (rem >= 16 - ti) { rem -= 16 - ti; ++ti; }
        int tj = ti + rem;
        const ushort* A = assignT + ((size_t)b * NP_ + ti * 64) * N_;
        const ushort* Bp = assignT + ((size_t)b * NP_ + tj * 64) * N_;
        f32x4 acc[2][2];
#pragma unroll
        for (int x = 0; x < 2; ++x)
#pragma unroll
            for (int y = 0; y < 2; ++y) acc[x][y] = (f32x4){0.f, 0.f, 0.f, 0.f};
        gemm64g(A, Bp, acc, lds);
        float lsum = 0.f;
#pragma unroll
        for (int x = 0; x < 2; ++x)
#pragma unroll
            for (int y = 0; y < 2; ++y)
#pragma unroll
                for (int v = 0; v < 4; ++v) lsum += acc[x][y][v] * acc[x][y][v];
        float bs = bsum256(red, t, lsum);
        if (t == 0) gram_partial[(size_t)b * 136 + idx] = (ti == tj ? 1.0f : 2.0f) * bs;
    } else if (bid < 1600) {
        // ---- pool64 body (identical) ----
        int sub = bid - 1088;
        int b = sub & 7;
        int tile = sub >> 3;
        int p0 = (tile >> 2) * 64, d0 = (tile & 3) * 64;
        const ushort* A = assignT + ((size_t)b * NP_ + p0) * N_;
        const ushort* Bp = tokT + ((size_t)b * D_ + d0) * N_;
        f32x4 acc[2][2];
#pragma unroll
        for (int x = 0; x < 2; ++x)
#pragma unroll
            for (int y = 0; y < 2; ++y) acc[x][y] = (f32x4){0.f, 0.f, 0.f, 0.f};
        gemm64g(A, Bp, acc, lds);
        int lane = t & 63;
        int wid = t >> 6;
        int wm = wid >> 1, wn = wid & 1;
#pragma unroll
        for (int fm = 0; fm < 2; ++fm)
#pragma unroll
            for (int fn = 0; fn < 2; ++fn) {
                int p = p0 + wm * 32 + fm * 16 + (lane >> 4) * 4;
                int d = d0 + wn * 32 + fn * 16 + (lane & 15);
#pragma unroll
                for (int v = 0; v < 4; ++v)
                    pooled[((size_t)b * NP_ + p + v) * D_ + d] = acc[fm][fn][v];
            }
    } else if (bid < 1856) {
        // ---- poolt_part body (identical) ----
        int sub = bid - 1600;
        int b = sub & 7, ck = sub >> 3;
        const float* A = assign + ((size_t)b * N_ + (size_t)ck * 64) * NP_;
        const float* T = tstamp + (size_t)b * N_ + (size_t)ck * 64;
        float4 acc = make_float4(0.f, 0.f, 0.f, 0.f);
        for (int n = 0; n < 64; ++n) {
            float4 v = *(const float4*)(A + (size_t)n * NP_ + t * 4);
            float tv = T[n];
            acc.x += v.x * tv; acc.y += v.y * tv; acc.z += v.z * tv; acc.w += v.w * tv;
        }
        *(float4*)(part + ((size_t)(b * 32 + ck)) * NP_ + t * 4) = acc;
    } else {
        // ---- edge body: 4 rows/block, one row per wave (per-wave code identical) ----
        int row = (bid - 1856) * 4 + (t >> 6);
        int lane = t & 63;
        int dgi = deg[row];
        int b = row >> 11;
        float acc = 0.f;
        if (dgi > 0) {
            const float* ai = assign + (size_t)row * NP_;
            float areg[16];
#pragma unroll
            for (int q = 0; q < 16; ++q) areg[q] = ai[q * 64 + lane];
            for (int k = 0; k < dgi; ++k) {
                int j = nbr[(size_t)row * K_ + k];
                const float* aj = assign + ((size_t)(b * N_ + j)) * NP_;
#pragma unroll
                for (int q = 0; q < 16; ++q) acc += areg[q] * aj[q * 64 + lane];
            }
        }
#pragma unroll
        for (int s = 32; s > 0; s >>= 1) acc += __shfl_down(acc, s);
        if (lane == 0) edge_partial[row] = acc;
    }
}

// ==== FUSED dispatch: sort (blocks 0..7) | fin (block 8) ====
__global__ __launch_bounds__(256) void k_sortfin(const float* __restrict__ part,
                                                 float* __restrict__ out_pt,
                                                 int* __restrict__ sortidx,
                                                 const float* __restrict__ gram_partial,
                                                 const float* __restrict__ edge_partial,
                                                 const float* __restrict__ ent_partial,
                                                 const int* __restrict__ deg,
                                                 float* __restrict__ out2) {
    int t = threadIdx.x;
    if (blockIdx.x == 8) {
        // ---- fin body (identical) ----
        __shared__ float red[256];
        float t1 = 0.f, t2 = 0.f, t3 = 0.f, ent = 0.f;
        for (int i = t; i < 136 * B_; i += 256) t1 += gram_partial[i];
        for (int i = t; i < B_ * N_; i += 256) t2 += edge_partial[i];
        for (int i = t; i < (B_ * N_) / 16; i += 256) ent += ent_partial[i];
        for (int i = t; i < B_ * N_; i += 256) t3 += (float)deg[i];
        t1 = bsum256(red, t, t1);
        t2 = bsum256(red, t, t2);
        t3 = bsum256(red, t, t3);
        ent = bsum256(red, t, ent);
        if (t == 0) {
            out2[0] = (t1 - 2.f * t2 + t3) / (float)((size_t)B_ * N_ * N_);
            out2[1] = ent / (float)(B_ * N_);
        }
        return;
    }
    // ---- sort body (identical: reduce partials then bitonic) ----
    int b = blockIdx.x;
    __shared__ float val[NP_];
    __shared__ int sidx[NP_];
    {
        float4 acc = make_float4(0.f, 0.f, 0.f, 0.f);
        for (int ck = 0; ck < 32; ++ck) {
            float4 v = *(const float4*)(part + ((size_t)(b * 32 + ck)) * NP_ + t * 4);
            acc.x += v.x; acc.y += v.y; acc.z += v.z; acc.w += v.w;
        }
        val[t * 4 + 0] = acc.x; val[t * 4 + 1] = acc.y;
        val[t * 4 + 2] = acc.z; val[t * 4 + 3] = acc.w;
        sidx[t * 4 + 0] = t * 4 + 0; sidx[t * 4 + 1] = t * 4 + 1;
        sidx[t * 4 + 2] = t * 4 + 2; sidx[t * 4 + 3] = t * 4 + 3;
    }
    __syncthreads();
    for (int k = 2; k <= NP_; k <<= 1) {
        for (int j = k >> 1; j > 0; j >>= 1) {
            for (int e = t; e < NP_; e += 256) {
                int l = e ^ j;
                if (l > e) {
                    bool up = ((e & k) == 0);
                    float v1 = val[e], v2 = val[l];
                    int i1 = sidx[e], i2 = sidx[l];
                    bool sw = up ? ((v1 > v2) || (v1 == v2 && i1 > i2))
                                 : ((v1 < v2) || (v1 == v2 && i1 < i2));
                    if (sw) { val[e] = v2; val[l] = v1; sidx[e] = i2; sidx[l] = i1; }
                }
            }
            __syncthreads();
        }
    }
    for (int e = t; e < NP_; e += 256) {
        out_pt[(size_t)b * NP_ + e] = val[e];
        sortidx[(size_t)b * NP_ + e] = sidx[e];
    }
}

// ---------------- gather pooled rows in sorted order ----------------
__global__ __launch_bounds__(64) void k_gather(const float* __restrict__ pooledU,
                                               const int* __restrict__ sortidx,
                                               float* __restrict__ out) {
    int bp = blockIdx.x;
    int b = bp >> 10;
    int src = sortidx[bp];
    const float4* s = (const float4*)(pooledU + ((size_t)(b << 10) + src) * D_);
    float4* d = (float4*)(out + (size_t)bp * D_);
    d[threadIdx.x] = s[threadIdx.x];
}

extern "C" void kernel_launch(void* const* d_in, const int* in_sizes, int n_in,
                              void* d_out, int out_size, void* d_ws, size_t ws_size,
                              hipStream_t stream) {
    const float* tokens = (const float*)d_in[0];
    const float* tstamp = (const float*)d_in[1];
    const float* W1 = (const float*)d_in[2];
    const float* b1 = (const float*)d_in[3];
    const float* W2 = (const float*)d_in[4];
    const float* b2 = (const float*)d_in[5];
    float* out = (float*)d_out;

    char* wsp = (char*)d_ws;
    size_t off = 0;
    auto alloc = [&](size_t bytes) -> void* {
        void* p = wsp + off;
        off += (bytes + 255) & ~(size_t)255;
        return p;
    };
    float* tn = (float*)alloc(sizeof(float) * (size_t)B_ * N_ * D_);      // 16.8 MB
    float* agg = tn;  // tn dead after k_rescore
    float* assign = (float*)alloc(sizeof(float) * (size_t)B_ * N_ * NP_); // 67.1 MB
    ushort* tnbf = (ushort*)alloc(sizeof(ushort) * (size_t)B_ * N_ * D_); // 8.4 MB
    ushort* tokT = tnbf;  // tnbf dead after k_simtop
    ushort* assignT = (ushort*)alloc(sizeof(ushort) * (size_t)B_ * NP_ * N_);  // 33.6 MB
    float* pooledU = (float*)alloc(sizeof(float) * (size_t)B_ * NP_ * D_);     // 8.4 MB
    float* poolt_part = (float*)alloc(sizeof(float) * (size_t)B_ * 32 * NP_);  // 1 MB
    int* candbuf = (int*)alloc(sizeof(int) * (size_t)B_ * N_ * 16);
    int* topkbuf = (int*)alloc(sizeof(int) * (size_t)B_ * N_ * K_);
    int* nbrbuf = (int*)alloc(sizeof(int) * (size_t)B_ * N_ * K_);
    int* degbuf = (int*)alloc(sizeof(int) * (size_t)B_ * N_);
    int* sortidx = (int*)alloc(sizeof(int) * (size_t)B_ * NP_);
    float* gram_p = (float*)alloc(sizeof(float) * 136 * B_);
    float* edge_p = (float*)alloc(sizeof(float) * (size_t)B_ * N_);
    float* ent_p = (float*)alloc(sizeof(float) * (size_t)(B_ * N_) / 16);

    k_norm<<<B_ * N_, 256, 0, stream>>>(tokens, tn, tnbf);
    k_simtop<<<512, 256, 0, stream>>>(tnbf, candbuf);
    k_rescore<<<B_ * N_, 64, 0, stream>>>(tn, candbuf, topkbuf);
    k_adj_agg<<<B_ * N_, 64, 0, stream>>>(tokens, topkbuf, nbrbuf, degbuf, agg);
    k_m12t<<<5120, 256, 0, stream>>>(tokens, agg, W1, b1, W2, b2, assign, ent_p, tokT);
    k_asT<<<dim3(N_ / 32, NP_ / 32, B_), 256, 0, stream>>>(assign, assignT);
    k_fuse4<<<5952, 256, 0, stream>>>(assignT, tokT, assign, tstamp, nbrbuf, degbuf,
                                      pooledU, poolt_part, gram_p, edge_p);
    k_sortfin<<<9, 256, 0, stream>>>(poolt_part, out + (size_t)B_ * NP_ * D_, sortidx,
                                     gram_p, edge_p, ent_p, degbuf,
                                     out + (size_t)B_ * NP_ * D_ + (size_t)B_ * NP_);
    k_gather<<<B_ * NP_, 64, 0, stream>>>(pooledU, sortidx, out);
}